// Round 11
// baseline (526.702 us; speedup 1.0000x reference)
//
#include <hip/hip_runtime.h>
#include <math.h>

#define NS 4096
#define CH 512
#define EPSV 1e-5f

typedef __attribute__((ext_vector_type(8))) _Float16 f16x8;  // 8 x fp16 MFMA operand
typedef __attribute__((ext_vector_type(4))) float f32x4;     // MFMA accumulator
typedef unsigned short u16;

// ---------- fp16 helpers (RNE via cast) ----------
__device__ __forceinline__ u16 f2h(float x) {
    _Float16 h = (_Float16)x;
    return __builtin_bit_cast(unsigned short, h);
}
__device__ __forceinline__ float h2f(u16 b) {
    return (float)__builtin_bit_cast(_Float16, b);
}

// ---------- async global->LDS, 16B per lane ----------
__device__ __forceinline__ void gload16(const void* g, void* l) {
    __builtin_amdgcn_global_load_lds((const __attribute__((address_space(1))) unsigned*)g,
                                     (__attribute__((address_space(3))) unsigned*)l, 16, 0, 0);
}

// per-z dispatch table. np[z] = planes staged (prefix of [Ahi, Bhi, Alo]):
//   np=2 -> out = Ahi*Bhi           (1 MFMA term)
//   np=3 -> out = (Ahi+Alo)*Bhi     (2 terms)
// mode: 0 = fp32 out (+bias, +resid), 1 = packed fp16 HI-ONLY out [K/8][N][8].
// coff: per-z offset (floats) into the group-scale table c (GS kernels only).
struct ZTab {
    long aoff[6];
    long boff[6];
    long ooff[6];
    long coff[6];
    int  mode[6];
    int  np[6];
    const float* bias[6];
};

// =====================================================================================
// kloop<NPZ,GS>: fully-unrolled compile-time staging + MFMA pipeline, 2-phase dbuf.
// GS: K split into groups of 128 (4 K-steps); per group, MFMA accumulates a PARTIAL
// (zero-C trick on the group's first MFMA), then tot += part * c[g][n] (per-lane n).
// Buffer indices are compile-time inside the unrolled 4-step group (round-8 lesson).
// =====================================================================================
template<int NPZ, bool GS>
__device__ __forceinline__ void kloop(
    const u16* __restrict__ pAhi, const u16* __restrict__ pAlo,
    const u16* __restrict__ pBhi,
    u16* smem, int smemStride,
    int Mw, int Nw, int K, int m0, int n0,
    int wid, int lane, int lk, int lm, int wm, int wn,
    const float* __restrict__ cbase, const int* nidx,
    f32x4 (&acc)[4][4])
{
    auto stage = [&](int buf, int ks) {
        const int kp0 = ks << 2;
        #pragma unroll
        for (int i = 0; i < 2 * NPZ; ++i) {
            const int q = i * 4 + wid;                 // wave-uniform
            const int b = q >> 3;                      // plane id (compile-time per i)
            const int p = (q & 7) >> 1;                // k-plane
            const int w = ((q & 1) << 6) + lane;       // width index 0..127
            const u16* src;
            if (b == 0)      src = pAhi + ((size_t)(kp0 + p) * Mw + m0 + w) * 8;
            else if (b == 1) src = pBhi + ((size_t)(kp0 + p) * Nw + n0 + w) * 8;
            else             src = pAlo + ((size_t)(kp0 + p) * Mw + m0 + w) * 8;
            gload16(src, &smem[(size_t)buf * smemStride + (size_t)(((b * 4 + p) * 128) + w) * 8]);
        }
    };
    auto frags = [&](int buf, f16x8 (&ah)[4], f16x8 (&bh)[4], f16x8 (&al)[4]) {
        const u16* sm = smem + (size_t)buf * smemStride;
        #pragma unroll
        for (int f = 0; f < 4; ++f) {
            ah[f] = *(const f16x8*)&sm[((0 * 4 + lk) * 128 + wm * 64 + f * 16 + lm) * 8];
            bh[f] = *(const f16x8*)&sm[((1 * 4 + lk) * 128 + wn * 64 + f * 16 + lm) * 8];
            if (NPZ == 3)
                al[f] = *(const f16x8*)&sm[((2 * 4 + lk) * 128 + wm * 64 + f * 16 + lm) * 8];
        }
    };

    const int nK = K >> 5;
    stage(0, 0);
    __syncthreads();                 // drains vmcnt(0): buf0 ready
    if constexpr (GS) {
        const f32x4 zf = {0.f, 0.f, 0.f, 0.f};
        const int nG = nK >> 2;      // 128-wide k-groups
        for (int g = 0; g < nG; ++g) {
            float cg[4];
            #pragma unroll
            for (int j = 0; j < 4; ++j)
                cg[j] = cbase[(size_t)g * NS + nidx[j]];
            f32x4 part[4][4];
            #pragma unroll
            for (int kk = 0; kk < 4; ++kk) {
                const int ks = g * 4 + kk;
                if (ks + 1 < nK) stage((kk & 1) ^ 1, ks + 1);
                f16x8 ah[4], bh[4], al[4];
                frags(kk & 1, ah, bh, al);
                #pragma unroll
                for (int i = 0; i < 4; ++i)
                    #pragma unroll
                    for (int j = 0; j < 4; ++j) {
                        part[i][j] = __builtin_amdgcn_mfma_f32_16x16x32_f16(
                            ah[i], bh[j], (kk == 0 ? zf : part[i][j]), 0, 0, 0);
                        if (NPZ == 3)
                            part[i][j] = __builtin_amdgcn_mfma_f32_16x16x32_f16(
                                al[i], bh[j], part[i][j], 0, 0, 0);
                    }
                __syncthreads();
            }
            #pragma unroll
            for (int i = 0; i < 4; ++i)
                #pragma unroll
                for (int j = 0; j < 4; ++j)
                    acc[i][j] += part[i][j] * cg[j];
        }
    } else {
        int cur = 0;
        for (int ks = 0; ks < nK; ++ks) {
            if (ks + 1 < nK) stage(cur ^ 1, ks + 1);
            f16x8 ah[4], bh[4], al[4];
            frags(cur, ah, bh, al);
            #pragma unroll
            for (int i = 0; i < 4; ++i)
                #pragma unroll
                for (int j = 0; j < 4; ++j) {
                    acc[i][j] = __builtin_amdgcn_mfma_f32_16x16x32_f16(ah[i], bh[j], acc[i][j], 0, 0, 0);
                    if (NPZ == 3)
                        acc[i][j] = __builtin_amdgcn_mfma_f32_16x16x32_f16(al[i], bh[j], acc[i][j], 0, 0, 0);
                }
            __syncthreads();
            cur ^= 1;
        }
    }
}

// =====================================================================================
// Split-fp16 GEMM:  out[m][n] = sum_k A[k][m] * B[k][n]
// Packed operand layout: element (k, x) at ((k>>3)*W + x)*8 + (k&7)
// Tile 128x128, BK=32, 4 waves (2x2), per-wave 64x64 via 4x4 frags of 16x16x32.
// COLST (QK): cross-wave 128-row-group softmax stats (max, sum(exp)) + stores
//   E16 = fp16(exp(acc - groupmax)) in packed layout.
// GS (PV): B = E16; per-128-group rescale by c[g][n] (see kloop).
// =====================================================================================
template<int NP, bool RESID, bool COLST, bool GS>
__global__ __launch_bounds__(256, (NP == 2 ? 4 : 3)) void gemm_split(
    const u16* __restrict__ Ahi, const u16* __restrict__ Alo,
    const u16* __restrict__ Bhi,
    const float* __restrict__ resid,
    float* __restrict__ outF, u16* __restrict__ outH,
    float* __restrict__ pmg, float* __restrict__ psg,
    const float* __restrict__ cb,
    int Mw, int Nw, int K, ZTab tab)
{
    __shared__ u16 smem[2][NP * 4 * 128 * 8];   // 2 x (NP*8KB) double buffer
    const int t = threadIdx.x;
    const int lane = t & 63;
    const int wid = t >> 6;
    const int wm = wid >> 1, wn = wid & 1;
    const int lk = lane >> 4, lm = lane & 15;
    const int m0 = blockIdx.y * 128, n0 = blockIdx.x * 128;
    const int z = blockIdx.z;
    const int npz = tab.np[z];
    const u16* pAhi = Ahi + tab.aoff[z];
    const u16* pAlo = Alo + tab.aoff[z];
    const u16* pBhi = Bhi + tab.boff[z];
    const float* cbase = GS ? (cb + tab.coff[z]) : nullptr;
    int nidx[4];
    #pragma unroll
    for (int j = 0; j < 4; ++j) nidx[j] = n0 + wn * 64 + j * 16 + lm;

    f32x4 acc[4][4] = {};
    const int smemStride = NP * 4 * 128 * 8;

    if constexpr (NP == 2) {
        kloop<2, GS>(pAhi, pAlo, pBhi, &smem[0][0], smemStride,
                     Mw, Nw, K, m0, n0, wid, lane, lk, lm, wm, wn, cbase, nidx, acc);
    } else {
        if (npz == 2)
            kloop<2, GS>(pAhi, pAlo, pBhi, &smem[0][0], smemStride,
                         Mw, Nw, K, m0, n0, wid, lane, lk, lm, wm, wn, cbase, nidx, acc);
        else
            kloop<3, GS>(pAhi, pAlo, pBhi, &smem[0][0], smemStride,
                         Mw, Nw, K, m0, n0, wid, lane, lk, lm, wm, wn, cbase, nidx, acc);
    }

    // ---- epilogue: C/D layout col = lane&15, row = (lane>>4)*4 + reg ----
    const float* bp = tab.bias[z];
    if (COLST) {
        // per-wave 64-row stats, combined across wm into 128-row groups via LDS.
        float* smx = (float*)&smem[0][0];          // [2][128]
        float* ssm = smx + 256;
        float mxw[4], smw[4];
        #pragma unroll
        for (int j = 0; j < 4; ++j) {
            float mx = -3.0e38f;
            #pragma unroll
            for (int i = 0; i < 4; ++i)
                #pragma unroll
                for (int r = 0; r < 4; ++r)
                    mx = fmaxf(mx, acc[i][j][r]);
            mx = fmaxf(mx, __shfl_xor(mx, 16));
            mx = fmaxf(mx, __shfl_xor(mx, 32));
            float sum = 0.f;
            #pragma unroll
            for (int i = 0; i < 4; ++i)
                #pragma unroll
                for (int r = 0; r < 4; ++r)
                    sum += __expf(acc[i][j][r] - mx);
            sum += __shfl_xor(sum, 16);
            sum += __shfl_xor(sum, 32);
            mxw[j] = mx; smw[j] = sum;
            if (lk == 0) {
                const int nloc = wn * 64 + j * 16 + lm;
                smx[wm * 128 + nloc] = mx;
                ssm[wm * 128 + nloc] = sum;
            }
        }
        __syncthreads();
        float mxc[4];
        #pragma unroll
        for (int j = 0; j < 4; ++j) {
            const int nloc = wn * 64 + j * 16 + lm;
            const float m0v = smx[nloc], m1v = smx[128 + nloc];
            const float mc = fmaxf(m0v, m1v);
            mxc[j] = mc;
            if (wm == 0 && lk == 0) {
                const float sc = ssm[nloc] * __expf(m0v - mc) + ssm[128 + nloc] * __expf(m1v - mc);
                const int n = n0 + nloc;
                const size_t gi = ((size_t)z * 32 + (m0 >> 7)) * NS + n;
                pmg[gi] = mc;
                psg[gi] = sc;
            }
        }
        // E16 store, packed layout (k=m): ((m>>3)*Nw + n)*8 + (m&7)
        u16* ph = outH + tab.ooff[z];
        #pragma unroll
        for (int i = 0; i < 4; ++i) {
            const long rg = (long)((m0 + wm * 64) >> 3) + i * 2 + (lk >> 1);
            const int sub = (lk & 1) * 4;
            #pragma unroll
            for (int j = 0; j < 4; ++j) {
                const int n = n0 + wn * 64 + j * 16 + lm;
                const long idx = (rg * Nw + n) * 8 + sub;
                u16 h[4];
                #pragma unroll
                for (int r = 0; r < 4; ++r)
                    h[r] = f2h(__expf(acc[i][j][r] - mxc[j]));
                *(ushort4*)&ph[idx] = make_ushort4(h[0], h[1], h[2], h[3]);
            }
        }
    } else if (tab.mode[z] == 0) {
        float* pout = outF + tab.ooff[z];
        #pragma unroll
        for (int i = 0; i < 4; ++i) {
            #pragma unroll
            for (int r = 0; r < 4; ++r) {
                const int m = m0 + wm * 64 + i * 16 + lk * 4 + r;
                const float bv = bp ? bp[m] : 0.f;
                const size_t ro = (size_t)m * Nw + n0 + wn * 64 + lm;
                #pragma unroll
                for (int j = 0; j < 4; ++j) {
                    float v = acc[i][j][r] + bv;
                    if (RESID) v += resid[tab.ooff[z] + ro + j * 16];
                    pout[ro + j * 16] = v;
                }
            }
        }
    } else {
        // packed fp16 hi-only out
        u16* ph = outH + tab.ooff[z];
        #pragma unroll
        for (int i = 0; i < 4; ++i) {
            float bv[4];
            #pragma unroll
            for (int r = 0; r < 4; ++r) {
                const int m = m0 + wm * 64 + i * 16 + lk * 4 + r;
                bv[r] = bp ? bp[m] : 0.f;
            }
            const long rg = (long)((m0 + wm * 64) >> 3) + i * 2 + (lk >> 1);
            const int sub = (lk & 1) * 4;
            #pragma unroll
            for (int j = 0; j < 4; ++j) {
                const int n = n0 + wn * 64 + j * 16 + lm;
                const long idx = (rg * Nw + n) * 8 + sub;
                u16 h[4];
                #pragma unroll
                for (int r = 0; r < 4; ++r)
                    h[r] = f2h(acc[i][j][r] + bv[r]);
                *(ushort4*)&ph[idx] = make_ushort4(h[0], h[1], h[2], h[3]);
            }
        }
    }
}

// =====================================================================================
// packB: fp32 [K][N] (batched) -> fp16 hi packed [K/8][N][8]. grid: (N/256, K/8, b)
// =====================================================================================
__global__ __launch_bounds__(256) void packB_k(const float* __restrict__ X,
    u16* __restrict__ Hi, int Nw, long xB, long pB)
{
    const int n = blockIdx.x * 256 + threadIdx.x;
    const int p = blockIdx.y;
    const int z = blockIdx.z;
    const float* Xp = X + (size_t)z * xB + ((size_t)p * 8) * Nw + n;
    u16 hi[8];
    #pragma unroll
    for (int j = 0; j < 8; ++j)
        hi[j] = f2h(Xp[(size_t)j * Nw]);
    const size_t o = (size_t)z * pB + ((size_t)p * Nw + n) * 8;
    *(uint4*)&Hi[o] = *(const uint4*)hi;
}

// =====================================================================================
// packA_T: weight W [M=512][K] fp32 -> transposed packed [K/8][512][8], HI only.
// grid: (K/64, 512/64)
// =====================================================================================
__global__ __launch_bounds__(256) void packA_T(const float* __restrict__ W,
    u16* __restrict__ Hi, int Kdim)
{
    __shared__ float tile[64][65];
    const int t = threadIdx.x;
    const int k0 = blockIdx.x * 64, m0 = blockIdx.y * 64;
    const int kk = t & 63, mb = t >> 6;
    #pragma unroll
    for (int it = 0; it < 16; ++it) {
        int mm = mb + it * 4;
        tile[mm][kk] = W[(size_t)(m0 + mm) * Kdim + k0 + kk];
    }
    __syncthreads();
    #pragma unroll
    for (int cc = 0; cc < 2; ++cc) {
        int c = t + cc * 256;
        int kp = c >> 6, m = c & 63;
        u16 hi[8];
        #pragma unroll
        for (int j = 0; j < 8; ++j)
            hi[j] = f2h(tile[m][kp * 8 + j]);
        size_t o = ((size_t)(k0 / 8 + kp) * CH + m0 + m) * 8;
        *(uint4*)&Hi[o] = *(const uint4*)hi;
    }
}

// =====================================================================================
// pack_hvT (quantized-moments form): Hv fp32 [C][N] ->
//   H1h = fp16(hv); H2h/H2l = hi/lo split of (fp16(hv))^2 (exact in fp32).
// grid: (N/64, C/64, 2=batch)
// =====================================================================================
__global__ __launch_bounds__(256) void pack_hvT(const float* __restrict__ Hv,
    u16* __restrict__ H1h, u16* __restrict__ H2h, u16* __restrict__ H2l)
{
    __shared__ float tile[64][65];
    const int t = threadIdx.x;
    const int s0 = blockIdx.x * 64, c0 = blockIdx.y * 64;
    const int z = blockIdx.z;
    const float* src = Hv + (size_t)z * CH * NS;
    const int ss = t & 63, cb = t >> 6;
    #pragma unroll
    for (int it = 0; it < 16; ++it) {
        int cc = cb + it * 4;
        tile[cc][ss] = src[(size_t)(c0 + cc) * NS + s0 + ss];
    }
    __syncthreads();
    const size_t zb = (size_t)z * NS * CH;
    #pragma unroll
    for (int cc2 = 0; cc2 < 2; ++cc2) {
        int c = t + cc2 * 256;
        int sp = c >> 6, cm = c & 63;
        u16 h1[8], h2[8], l2[8];
        #pragma unroll
        for (int j = 0; j < 8; ++j) {
            float v = tile[cm][sp * 8 + j];
            u16 a = f2h(v);
            h1[j] = a;
            float q = h2f(a);
            float q2 = q * q;
            u16 b = f2h(q2);
            h2[j] = b;
            l2[j] = f2h(q2 - h2f(b));
        }
        size_t o = zb + ((size_t)(s0 / 8 + sp) * CH + c0 + cm) * 8;
        *(uint4*)&H1h[o] = *(const uint4*)h1;
        *(uint4*)&H2h[o] = *(const uint4*)h2;
        *(uint4*)&H2l[o] = *(const uint4*)l2;
    }
}

// =====================================================================================
// colstats_comb32: combine 32 row-group partials -> column max + 1/sum. grid (16, 2)
// =====================================================================================
__global__ __launch_bounds__(256) void colstats_comb32(const float* __restrict__ pm,
    const float* __restrict__ ps, float* __restrict__ mx, float* __restrict__ inv)
{
    const int n = blockIdx.x * 256 + threadIdx.x;
    const int z = blockIdx.y;
    float m = -3.0e38f, s = 0.f;
    #pragma unroll 8
    for (int g = 0; g < 32; ++g) {
        float gm = pm[((size_t)z * 32 + g) * NS + n], gs = ps[((size_t)z * 32 + g) * NS + n];
        float nm = fmaxf(m, gm);
        s = s * __expf(m - nm) + gs * __expf(gm - nm);
        m = nm;
    }
    mx[(size_t)z * NS + n] = m;
    inv[(size_t)z * NS + n] = 1.f / s;
}

// =====================================================================================
// scale_c: c[z][g][n] = exp(pm - mxv) * invv   (PV group rescale table, 1 MB)
// grid: (16, 32, 2)
// =====================================================================================
__global__ __launch_bounds__(256) void scale_c(const float* __restrict__ pm,
    const float* __restrict__ mxv, const float* __restrict__ invv,
    float* __restrict__ c)
{
    const int n = blockIdx.x * 256 + threadIdx.x;
    const int g = blockIdx.y;
    const int z = blockIdx.z;
    const size_t gi = ((size_t)z * 32 + g) * NS + n;
    c[gi] = __expf(pm[gi] - mxv[(size_t)z * NS + n]) * invv[(size_t)z * NS + n];
}

// ================= per-(b,c) content stats =================
__global__ __launch_bounds__(256) void content_stats(const float* __restrict__ content,
                                                     float* __restrict__ cmean,
                                                     float* __restrict__ cinv)
{
    const int bc = blockIdx.x;
    const float4* p = (const float4*)(content + (size_t)bc * NS);
    const int t = threadIdx.x;
    float s = 0.f, s2 = 0.f;
    #pragma unroll
    for (int j = 0; j < 4; ++j) {
        float4 v = p[t + j * 256];
        s  += (v.x + v.y) + (v.z + v.w);
        s2 += (v.x * v.x + v.y * v.y) + (v.z * v.z + v.w * v.w);
    }
    #pragma unroll
    for (int off = 32; off >= 1; off >>= 1) {
        s  += __shfl_xor(s, off);
        s2 += __shfl_xor(s2, off);
    }
    __shared__ float r1[4], r2[4];
    const int wid = t >> 6;
    if ((t & 63) == 0) { r1[wid] = s; r2[wid] = s2; }
    __syncthreads();
    if (t == 0) {
        s  = (r1[0] + r1[1]) + (r1[2] + r1[3]);
        s2 = (r2[0] + r2[1]) + (r2[2] + r2[3]);
        const float mean = s * (1.0f / 4096.f);
        const float var = (s2 - 4096.f * mean * mean) * (1.0f / 4095.f);
        cmean[bc] = mean;
        cinv[bc] = rsqrtf(fmaxf(var, 0.f) + EPSV);
    }
}

// =====================================================================================
// compute_O + fused O-pack (hi only). grid: (NS/256, CH/8, 2)
// =====================================================================================
__global__ __launch_bounds__(256) void compute_O_pack(
    const float* __restrict__ Mean, const float* __restrict__ Sec,
    const float* __restrict__ content,
    const float* __restrict__ cmean, const float* __restrict__ cinv,
    u16* __restrict__ Oh)
{
    const int n  = blockIdx.x * 256 + threadIdx.x;
    const int cg = blockIdx.y;
    const int b  = blockIdx.z;
    const size_t KN = (size_t)CH * NS;
    u16 h[8];
    #pragma unroll
    for (int j = 0; j < 8; ++j) {
        const int c = cg * 8 + j;
        const size_t po = (size_t)b * KN + (size_t)c * NS + n;
        const float mn = Mean[po];
        const float sc = Sec[po];
        const float ct = content[po];
        const int bc = b * CH + c;
        const float o = sqrtf(fmaxf(sc - mn * mn, 0.f)) * ((ct - cmean[bc]) * cinv[bc]) + mn;
        h[j] = f2h(o);
    }
    const size_t off = (size_t)b * KN + ((size_t)cg * NS + n) * 8;
    *(uint4*)&Oh[off] = *(const uint4*)h;
}

// =====================================================================================
extern "C" void kernel_launch(void* const* d_in, const int* in_sizes, int n_in,
                              void* d_out, int out_size, void* d_ws, size_t ws_size,
                              hipStream_t stream)
{
    const float* content = (const float*)d_in[0];
    const float* style   = (const float*)d_in[1];
    const float* f_w   = (const float*)d_in[2];
    const float* f_b   = (const float*)d_in[3];
    const float* g_w   = (const float*)d_in[4];
    const float* g_b   = (const float*)d_in[5];
    const float* h_w   = (const float*)d_in[6];
    const float* h_b   = (const float*)d_in[7];
    const float* out_w = (const float*)d_in[8];
    const float* out_b = (const float*)d_in[9];
    float* out = (float*)d_out;

    char* ws = (char*)d_ws;
    size_t off = 0;
    auto alloc = [&](size_t bytes) -> void* {
        void* p = ws + off;
        off = (off + bytes + 255) & ~(size_t)255;
        return p;
    };

    const size_t KN   = (size_t)CH * NS;      // 2,097,152 elements (one batch plane)
    const size_t CHCH = (size_t)CH * CH;
    const long   NSNS = (long)NS * NS;

    // ---- weight packs: hi-only, contiguous [Wh0 Wh1 Wh2 Wh3] ----
    u16* Wh0 = (u16*)alloc(4 * CHCH * 2);
    u16* Whv[4] = { Wh0, Wh0 + CHCH, Wh0 + 2 * CHCH, Wh0 + 3 * CHCH };

    // ---- R2: two time-disjoint layouts:
    //   phase 1 (conv inputs, hi-only):  [Xc_hi | Xs_hi]               (each 2KN)
    //   phase 2 (PV A-packs):            [HvT_hi | Hv2T_hi | Hv2T_lo] (each 2KN)
    u16* R2 = (u16*)alloc(6 * KN * 2);
    u16* Xc_hi = R2;
    u16* Xs_hi = R2 + 2 * KN;
    u16* HvT_hi  = R2;
    u16* Hv2T_hi = R2 + 2 * KN;
    u16* Hv2T_lo = R2 + 4 * KN;

    // ---- R3: [Fqp_hi | Gkp_hi], each 2KN u16; Gkp reused as O pack ----
    u16* Fqp_hi = (u16*)alloc(2 * KN * 2);
    u16* Gkp_hi = (u16*)alloc(2 * KN * 2);
    u16* Op_hi  = Gkp_hi;

    // ---- R5: union: Hv32 fp32 (during convs) -> E16 both batches (67 MB) ----
    char* R5 = (char*)alloc(2 * (size_t)NS * NS * 2);
    float* Hv32 = (float*)(R5 + 4 * KN * 4);   // conv z=4,5 output (dead after pack_hvT)
    u16*   E16  = (u16*)R5;                    // QK output: fp16(exp(s - groupmax)), packed

    // ---- R6: Mean/Sec fp32, contiguous ----
    float* Mean32 = (float*)alloc(2 * KN * 4);
    float* Sec32  = (float*)alloc(2 * KN * 4);

    // ---- small ----
    float* pm    = (float*)alloc(2 * 32 * NS * 4);
    float* ps    = (float*)alloc(2 * 32 * NS * 4);
    float* mxv   = (float*)alloc(2 * NS * 4);
    float* invv  = (float*)alloc(2 * NS * 4);
    float* ctab  = (float*)alloc(2 * 32 * NS * 4);
    float* cmean = (float*)alloc(1024 * 4);
    float* cinv  = (float*)alloc(1024 * 4);
    (void)ws_size; (void)in_sizes; (void)n_in; (void)out_size;

    // ================= pipeline =================
    packA_T<<<dim3(8, 8), 256, 0, stream>>>(f_w,   Whv[0], CH);
    packA_T<<<dim3(8, 8), 256, 0, stream>>>(g_w,   Whv[1], CH);
    packA_T<<<dim3(8, 8), 256, 0, stream>>>(h_w,   Whv[2], CH);
    packA_T<<<dim3(8, 8), 256, 0, stream>>>(out_w, Whv[3], CH);
    packB_k<<<dim3(16, 64, 2), 256, 0, stream>>>(content, Xc_hi, NS, (long)KN, (long)KN);
    packB_k<<<dim3(16, 64, 2), 256, 0, stream>>>(style,   Xs_hi, NS, (long)KN, (long)KN);
    content_stats<<<1024, 256, 0, stream>>>(content, cmean, cinv);

    // ---- merged conv3 (1-term, np=2: Whi*Xhi): z = w*2 + b;
    //      w=0 (f,content)->Fqp hi, w=1 (g,style)->Gkp hi, w=2 (h,style)->Hv32 fp32 ----
    {
        ZTab tb = {};
        const float* bs[3] = { f_b, g_b, h_b };
        for (int z = 0; z < 6; ++z) {
            const int w = z >> 1, b = z & 1;
            tb.aoff[z] = (long)w * CHCH;
            tb.boff[z] = (w == 0 ? 0 : (long)(2 * KN)) + (long)b * KN;
            tb.mode[z] = (w < 2) ? 1 : 0;
            tb.np[z]   = 2;
            tb.ooff[z] = (w < 2) ? ((long)w * 2 * KN + (long)b * KN)   // u16 elems from Fqp_hi
                                 : ((long)4 * KN + (long)b * KN);      // fp32 elems from R5
            tb.bias[z] = bs[w];
        }
        gemm_split<2, false, false, false><<<dim3(32, 4, 6), 256, 0, stream>>>(
            Wh0, nullptr, Xc_hi, nullptr,
            (float*)R5, Fqp_hi, nullptr, nullptr, nullptr, CH, NS, CH, tb);
    }

    // quantized-moments Hv packs (overwrites R2 phase-1; Xc/Xs dead)
    pack_hvT<<<dim3(64, 8, 2), 256, 0, stream>>>(Hv32, HvT_hi, Hv2T_hi, Hv2T_lo);

    // ---- merged QK (1-term, np=2, z=2): E16 = fp16(exp(S - 128-group max)), packed;
    //      fused per-128-group col-stats (cross-wave combine in epilogue) ----
    {
        ZTab tq = {};
        for (int z = 0; z < 2; ++z) {
            tq.aoff[z] = (long)z * KN;     // Gk batch
            tq.boff[z] = (long)z * KN;     // Fq batch
            tq.ooff[z] = (long)z * NSNS;   // E16 batch (u16 elems)
            tq.np[z]   = 2;
        }
        gemm_split<2, false, true, false><<<dim3(32, 32, 2), 256, 0, stream>>>(
            Gkp_hi, nullptr, Fqp_hi, nullptr,
            nullptr, E16, pm, ps, nullptr, NS, NS, CH, tq);
    }
    colstats_comb32<<<dim3(16, 2), 256, 0, stream>>>(pm, ps, mxv, invv);
    scale_c<<<dim3(16, 32, 2), 256, 0, stream>>>(pm, mxv, invv, ctab);

    // ---- merged PV (GS): z=0,1 -> Mean (A=HvT_hi, np=2); z=2,3 -> Sec (np=3);
    //      B = E16, per-128-group rescale by ctab ----
    {
        ZTab tp = {};
        for (int z = 0; z < 4; ++z) {
            const int sec = (z >> 1), b = z & 1;
            tp.aoff[z] = (long)sec * 2 * KN + (long)b * KN;   // Ahi base R2; Alo base R2+2KN
            tp.boff[z] = (long)b * NSNS;
            tp.ooff[z] = (long)sec * 2 * KN + (long)b * KN;   // Mean32 / Sec32
            tp.coff[z] = (long)b * 32 * NS;
            tp.np[z]   = sec ? 3 : 2;
        }
        gemm_split<3, false, false, true><<<dim3(32, 4, 4), 256, 0, stream>>>(
            R2, R2 + 2 * KN, E16, nullptr,
            Mean32, nullptr, nullptr, nullptr, ctab, CH, NS, NS, tp);
    }

    // O + fused pack (fp16 hi only)
    compute_O_pack<<<dim3(16, 64, 2), 256, 0, stream>>>(
        Mean32, Sec32, content, cmean, cinv, Op_hi);

    // ---- out conv (1-term, np=2: Whi*O_hi): bias + residual(content) -> d_out ----
    {
        ZTab tf = {};
        for (int z = 0; z < 2; ++z) {
            tf.ooff[z] = (long)z * KN;
            tf.boff[z] = (long)z * KN;
            tf.np[z]   = 2;
            tf.bias[z] = out_b;
        }
        gemm_split<2, true, false, false><<<dim3(32, 4, 2), 256, 0, stream>>>(
            Whv[3], nullptr, Op_hi, content,
            out, nullptr, nullptr, nullptr, nullptr, CH, NS, CH, tf);
    }
}

// Round 12
// 245.551 us; speedup vs baseline: 2.1450x; 2.1450x over previous
//
#include <hip/hip_runtime.h>
#include <math.h>

#define NS 4096
#define CH 512
#define EPSV 1e-5f

typedef __attribute__((ext_vector_type(8))) _Float16 f16x8;  // 8 x fp16 MFMA operand
typedef __attribute__((ext_vector_type(4))) float f32x4;     // MFMA accumulator
typedef unsigned short u16;

// ---------- fp16 helpers (RNE via cast) ----------
__device__ __forceinline__ u16 f2h(float x) {
    _Float16 h = (_Float16)x;
    return __builtin_bit_cast(unsigned short, h);
}
__device__ __forceinline__ float h2f(u16 b) {
    return (float)__builtin_bit_cast(_Float16, b);
}

// ---------- async global->LDS, 16B per lane ----------
__device__ __forceinline__ void gload16(const void* g, void* l) {
    __builtin_amdgcn_global_load_lds((const __attribute__((address_space(1))) unsigned*)g,
                                     (__attribute__((address_space(3))) unsigned*)l, 16, 0, 0);
}

// per-z dispatch table. np[z] = planes staged (prefix of [Ahi, Bhi, Alo]):
//   np=2 -> out = Ahi*Bhi           (1 MFMA term)
//   np=3 -> out = (Ahi+Alo)*Bhi     (2 terms)
// mode: 0 = fp32 out (+bias, +resid), 1 = packed fp16 HI-ONLY out [K/8][N][8].
// coff: per-z offset (floats) into the group-scale table c (GS kernels only).
struct ZTab {
    long aoff[6];
    long boff[6];
    long ooff[6];
    long coff[6];
    int  mode[6];
    int  np[6];
    const float* bias[6];
};

// =====================================================================================
// kloop<NPZ,GS>: fully-unrolled compile-time staging + MFMA pipeline, 2-phase dbuf.
// GS (PV): B = E16 = fp16(exp(s - groupmax_g)). Per 128-wide k-group g, the B
// fragment (one column n per lane) is scaled by ch = fp16(c[g][n]) BEFORE the MFMA
// (v_pk_mul_f16, VALU pipe) -- mathematically identical to scaling the partial sum,
// but needs NO second accumulator bank (round-11 spill lesson).
// =====================================================================================
template<int NPZ, bool GS>
__device__ __forceinline__ void kloop(
    const u16* __restrict__ pAhi, const u16* __restrict__ pAlo,
    const u16* __restrict__ pBhi,
    u16* smem, int smemStride,
    int Mw, int Nw, int K, int m0, int n0,
    int wid, int lane, int lk, int lm, int wm, int wn,
    const float* __restrict__ cbase,
    f32x4 (&acc)[4][4])
{
    auto stage = [&](int buf, int ks) {
        const int kp0 = ks << 2;
        #pragma unroll
        for (int i = 0; i < 2 * NPZ; ++i) {
            const int q = i * 4 + wid;                 // wave-uniform
            const int b = q >> 3;                      // plane id (compile-time per i)
            const int p = (q & 7) >> 1;                // k-plane
            const int w = ((q & 1) << 6) + lane;       // width index 0..127
            const u16* src;
            if (b == 0)      src = pAhi + ((size_t)(kp0 + p) * Mw + m0 + w) * 8;
            else if (b == 1) src = pBhi + ((size_t)(kp0 + p) * Nw + n0 + w) * 8;
            else             src = pAlo + ((size_t)(kp0 + p) * Mw + m0 + w) * 8;
            gload16(src, &smem[(size_t)buf * smemStride + (size_t)(((b * 4 + p) * 128) + w) * 8]);
        }
    };

    const int nK = K >> 5;
    stage(0, 0);
    __syncthreads();                 // drains vmcnt(0): buf0 ready
    int cur = 0;
    _Float16 ch[4] = {};
    for (int ks = 0; ks < nK; ++ks) {
        if (GS && (ks & 3) == 0) {
            const int g = ks >> 2;
            #pragma unroll
            for (int j = 0; j < 4; ++j)
                ch[j] = (_Float16)cbase[(size_t)g * NS + n0 + wn * 64 + j * 16 + lm];
        }
        if (ks + 1 < nK) stage(cur ^ 1, ks + 1);   // prefetch next tile during MFMA
        const u16* sm = smem + (size_t)cur * smemStride;
        f16x8 ah[4], bh[4], al[4];
        #pragma unroll
        for (int f = 0; f < 4; ++f) {
            ah[f] = *(const f16x8*)&sm[((0 * 4 + lk) * 128 + wm * 64 + f * 16 + lm) * 8];
            bh[f] = *(const f16x8*)&sm[((1 * 4 + lk) * 128 + wn * 64 + f * 16 + lm) * 8];
            if (GS) bh[f] = bh[f] * ch[f];          // splat scalar, v_pk_mul_f16
            if (NPZ == 3)
                al[f] = *(const f16x8*)&sm[((2 * 4 + lk) * 128 + wm * 64 + f * 16 + lm) * 8];
        }
        #pragma unroll
        for (int i = 0; i < 4; ++i)
            #pragma unroll
            for (int j = 0; j < 4; ++j) {
                acc[i][j] = __builtin_amdgcn_mfma_f32_16x16x32_f16(ah[i], bh[j], acc[i][j], 0, 0, 0);
                if (NPZ == 3)
                    acc[i][j] = __builtin_amdgcn_mfma_f32_16x16x32_f16(al[i], bh[j], acc[i][j], 0, 0, 0);
            }
        __syncthreads();             // prefetched buffer complete, reads done
        cur ^= 1;
    }
}

// =====================================================================================
// Split-fp16 GEMM:  out[m][n] = sum_k A[k][m] * B[k][n]
// Packed operand layout: element (k, x) at ((k>>3)*W + x)*8 + (k&7)
// Tile 128x128, BK=32, 4 waves (2x2), per-wave 64x64 via 4x4 frags of 16x16x32.
// COLST (QK): cross-wave 128-row-group softmax stats (max, sum(exp)) + stores
//   E16 = fp16(exp(acc - groupmax)) in packed layout.
// GS (PV): B = E16, per-128-group fragment rescale by c[g][n] (see kloop).
// =====================================================================================
template<int NP, bool RESID, bool COLST, bool GS>
__global__ __launch_bounds__(256, (NP == 2 ? 4 : 3)) void gemm_split(
    const u16* __restrict__ Ahi, const u16* __restrict__ Alo,
    const u16* __restrict__ Bhi,
    const float* __restrict__ resid,
    float* __restrict__ outF, u16* __restrict__ outH,
    float* __restrict__ pmg, float* __restrict__ psg,
    const float* __restrict__ cb,
    int Mw, int Nw, int K, ZTab tab)
{
    __shared__ u16 smem[2][NP * 4 * 128 * 8];   // 2 x (NP*8KB) double buffer
    const int t = threadIdx.x;
    const int lane = t & 63;
    const int wid = t >> 6;
    const int wm = wid >> 1, wn = wid & 1;
    const int lk = lane >> 4, lm = lane & 15;
    const int m0 = blockIdx.y * 128, n0 = blockIdx.x * 128;
    const int z = blockIdx.z;
    const int npz = tab.np[z];
    const u16* pAhi = Ahi + tab.aoff[z];
    const u16* pAlo = Alo + tab.aoff[z];
    const u16* pBhi = Bhi + tab.boff[z];
    const float* cbase = GS ? (cb + tab.coff[z]) : nullptr;

    f32x4 acc[4][4] = {};
    const int smemStride = NP * 4 * 128 * 8;

    if constexpr (NP == 2) {
        kloop<2, GS>(pAhi, pAlo, pBhi, &smem[0][0], smemStride,
                     Mw, Nw, K, m0, n0, wid, lane, lk, lm, wm, wn, cbase, acc);
    } else {
        if (npz == 2)
            kloop<2, GS>(pAhi, pAlo, pBhi, &smem[0][0], smemStride,
                         Mw, Nw, K, m0, n0, wid, lane, lk, lm, wm, wn, cbase, acc);
        else
            kloop<3, GS>(pAhi, pAlo, pBhi, &smem[0][0], smemStride,
                         Mw, Nw, K, m0, n0, wid, lane, lk, lm, wm, wn, cbase, acc);
    }

    // ---- epilogue: C/D layout col = lane&15, row = (lane>>4)*4 + reg ----
    const float* bp = tab.bias[z];
    if (COLST) {
        // per-wave 64-row stats, combined across wm into 128-row groups via LDS.
        float* smx = (float*)&smem[0][0];          // [2][128]
        float* ssm = smx + 256;
        #pragma unroll
        for (int j = 0; j < 4; ++j) {
            float mx = -3.0e38f;
            #pragma unroll
            for (int i = 0; i < 4; ++i)
                #pragma unroll
                for (int r = 0; r < 4; ++r)
                    mx = fmaxf(mx, acc[i][j][r]);
            mx = fmaxf(mx, __shfl_xor(mx, 16));
            mx = fmaxf(mx, __shfl_xor(mx, 32));
            float sum = 0.f;
            #pragma unroll
            for (int i = 0; i < 4; ++i)
                #pragma unroll
                for (int r = 0; r < 4; ++r)
                    sum += __expf(acc[i][j][r] - mx);
            sum += __shfl_xor(sum, 16);
            sum += __shfl_xor(sum, 32);
            if (lk == 0) {
                const int nloc = wn * 64 + j * 16 + lm;
                smx[wm * 128 + nloc] = mx;
                ssm[wm * 128 + nloc] = sum;
            }
        }
        __syncthreads();
        float mxc[4];
        #pragma unroll
        for (int j = 0; j < 4; ++j) {
            const int nloc = wn * 64 + j * 16 + lm;
            const float m0v = smx[nloc], m1v = smx[128 + nloc];
            const float mc = fmaxf(m0v, m1v);
            mxc[j] = mc;
            if (wm == 0 && lk == 0) {
                const float sc = ssm[nloc] * __expf(m0v - mc) + ssm[128 + nloc] * __expf(m1v - mc);
                const int n = n0 + nloc;
                const size_t gi = ((size_t)z * 32 + (m0 >> 7)) * NS + n;
                pmg[gi] = mc;
                psg[gi] = sc;
            }
        }
        // E16 store, packed layout (k=m): ((m>>3)*Nw + n)*8 + (m&7)
        u16* ph = outH + tab.ooff[z];
        #pragma unroll
        for (int i = 0; i < 4; ++i) {
            const long rg = (long)((m0 + wm * 64) >> 3) + i * 2 + (lk >> 1);
            const int sub = (lk & 1) * 4;
            #pragma unroll
            for (int j = 0; j < 4; ++j) {
                const int n = n0 + wn * 64 + j * 16 + lm;
                const long idx = (rg * Nw + n) * 8 + sub;
                u16 h[4];
                #pragma unroll
                for (int r = 0; r < 4; ++r)
                    h[r] = f2h(__expf(acc[i][j][r] - mxc[j]));
                *(ushort4*)&ph[idx] = make_ushort4(h[0], h[1], h[2], h[3]);
            }
        }
    } else if (tab.mode[z] == 0) {
        float* pout = outF + tab.ooff[z];
        #pragma unroll
        for (int i = 0; i < 4; ++i) {
            #pragma unroll
            for (int r = 0; r < 4; ++r) {
                const int m = m0 + wm * 64 + i * 16 + lk * 4 + r;
                const float bv = bp ? bp[m] : 0.f;
                const size_t ro = (size_t)m * Nw + n0 + wn * 64 + lm;
                #pragma unroll
                for (int j = 0; j < 4; ++j) {
                    float v = acc[i][j][r] + bv;
                    if (RESID) v += resid[tab.ooff[z] + ro + j * 16];
                    pout[ro + j * 16] = v;
                }
            }
        }
    } else {
        // packed fp16 hi-only out
        u16* ph = outH + tab.ooff[z];
        #pragma unroll
        for (int i = 0; i < 4; ++i) {
            float bv[4];
            #pragma unroll
            for (int r = 0; r < 4; ++r) {
                const int m = m0 + wm * 64 + i * 16 + lk * 4 + r;
                bv[r] = bp ? bp[m] : 0.f;
            }
            const long rg = (long)((m0 + wm * 64) >> 3) + i * 2 + (lk >> 1);
            const int sub = (lk & 1) * 4;
            #pragma unroll
            for (int j = 0; j < 4; ++j) {
                const int n = n0 + wn * 64 + j * 16 + lm;
                const long idx = (rg * Nw + n) * 8 + sub;
                u16 h[4];
                #pragma unroll
                for (int r = 0; r < 4; ++r)
                    h[r] = f2h(acc[i][j][r] + bv[r]);
                *(ushort4*)&ph[idx] = make_ushort4(h[0], h[1], h[2], h[3]);
            }
        }
    }
}

// =====================================================================================
// packB: fp32 [K][N] (batched) -> fp16 hi packed [K/8][N][8]. grid: (N/256, K/8, b)
// =====================================================================================
__global__ __launch_bounds__(256) void packB_k(const float* __restrict__ X,
    u16* __restrict__ Hi, int Nw, long xB, long pB)
{
    const int n = blockIdx.x * 256 + threadIdx.x;
    const int p = blockIdx.y;
    const int z = blockIdx.z;
    const float* Xp = X + (size_t)z * xB + ((size_t)p * 8) * Nw + n;
    u16 hi[8];
    #pragma unroll
    for (int j = 0; j < 8; ++j)
        hi[j] = f2h(Xp[(size_t)j * Nw]);
    const size_t o = (size_t)z * pB + ((size_t)p * Nw + n) * 8;
    *(uint4*)&Hi[o] = *(const uint4*)hi;
}

// =====================================================================================
// packA_T: weight W [M=512][K] fp32 -> transposed packed [K/8][512][8], HI only.
// grid: (K/64, 512/64)
// =====================================================================================
__global__ __launch_bounds__(256) void packA_T(const float* __restrict__ W,
    u16* __restrict__ Hi, int Kdim)
{
    __shared__ float tile[64][65];
    const int t = threadIdx.x;
    const int k0 = blockIdx.x * 64, m0 = blockIdx.y * 64;
    const int kk = t & 63, mb = t >> 6;
    #pragma unroll
    for (int it = 0; it < 16; ++it) {
        int mm = mb + it * 4;
        tile[mm][kk] = W[(size_t)(m0 + mm) * Kdim + k0 + kk];
    }
    __syncthreads();
    #pragma unroll
    for (int cc = 0; cc < 2; ++cc) {
        int c = t + cc * 256;
        int kp = c >> 6, m = c & 63;
        u16 hi[8];
        #pragma unroll
        for (int j = 0; j < 8; ++j)
            hi[j] = f2h(tile[m][kp * 8 + j]);
        size_t o = ((size_t)(k0 / 8 + kp) * CH + m0 + m) * 8;
        *(uint4*)&Hi[o] = *(const uint4*)hi;
    }
}

// =====================================================================================
// pack_hvT (quantized-moments form): Hv fp32 [C][N] ->
//   H1h = fp16(hv); H2h/H2l = hi/lo split of (fp16(hv))^2 (exact in fp32).
// grid: (N/64, C/64, 2=batch)
// =====================================================================================
__global__ __launch_bounds__(256) void pack_hvT(const float* __restrict__ Hv,
    u16* __restrict__ H1h, u16* __restrict__ H2h, u16* __restrict__ H2l)
{
    __shared__ float tile[64][65];
    const int t = threadIdx.x;
    const int s0 = blockIdx.x * 64, c0 = blockIdx.y * 64;
    const int z = blockIdx.z;
    const float* src = Hv + (size_t)z * CH * NS;
    const int ss = t & 63, cb = t >> 6;
    #pragma unroll
    for (int it = 0; it < 16; ++it) {
        int cc = cb + it * 4;
        tile[cc][ss] = src[(size_t)(c0 + cc) * NS + s0 + ss];
    }
    __syncthreads();
    const size_t zb = (size_t)z * NS * CH;
    #pragma unroll
    for (int cc2 = 0; cc2 < 2; ++cc2) {
        int c = t + cc2 * 256;
        int sp = c >> 6, cm = c & 63;
        u16 h1[8], h2[8], l2[8];
        #pragma unroll
        for (int j = 0; j < 8; ++j) {
            float v = tile[cm][sp * 8 + j];
            u16 a = f2h(v);
            h1[j] = a;
            float q = h2f(a);
            float q2 = q * q;
            u16 b = f2h(q2);
            h2[j] = b;
            l2[j] = f2h(q2 - h2f(b));
        }
        size_t o = zb + ((size_t)(s0 / 8 + sp) * CH + c0 + cm) * 8;
        *(uint4*)&H1h[o] = *(const uint4*)h1;
        *(uint4*)&H2h[o] = *(const uint4*)h2;
        *(uint4*)&H2l[o] = *(const uint4*)l2;
    }
}

// =====================================================================================
// colstats_comb32: combine 32 row-group partials -> column max + 1/sum. grid (16, 2)
// =====================================================================================
__global__ __launch_bounds__(256) void colstats_comb32(const float* __restrict__ pm,
    const float* __restrict__ ps, float* __restrict__ mx, float* __restrict__ inv)
{
    const int n = blockIdx.x * 256 + threadIdx.x;
    const int z = blockIdx.y;
    float m = -3.0e38f, s = 0.f;
    #pragma unroll 8
    for (int g = 0; g < 32; ++g) {
        float gm = pm[((size_t)z * 32 + g) * NS + n], gs = ps[((size_t)z * 32 + g) * NS + n];
        float nm = fmaxf(m, gm);
        s = s * __expf(m - nm) + gs * __expf(gm - nm);
        m = nm;
    }
    mx[(size_t)z * NS + n] = m;
    inv[(size_t)z * NS + n] = 1.f / s;
}

// =====================================================================================
// scale_c: c[z][g][n] = exp(pm - mxv) * invv   (PV group rescale table, 1 MB)
// grid: (16, 32, 2)
// =====================================================================================
__global__ __launch_bounds__(256) void scale_c(const float* __restrict__ pm,
    const float* __restrict__ mxv, const float* __restrict__ invv,
    float* __restrict__ c)
{
    const int n = blockIdx.x * 256 + threadIdx.x;
    const int g = blockIdx.y;
    const int z = blockIdx.z;
    const size_t gi = ((size_t)z * 32 + g) * NS + n;
    c[gi] = __expf(pm[gi] - mxv[(size_t)z * NS + n]) * invv[(size_t)z * NS + n];
}

// ================= per-(b,c) content stats =================
__global__ __launch_bounds__(256) void content_stats(const float* __restrict__ content,
                                                     float* __restrict__ cmean,
                                                     float* __restrict__ cinv)
{
    const int bc = blockIdx.x;
    const float4* p = (const float4*)(content + (size_t)bc * NS);
    const int t = threadIdx.x;
    float s = 0.f, s2 = 0.f;
    #pragma unroll
    for (int j = 0; j < 4; ++j) {
        float4 v = p[t + j * 256];
        s  += (v.x + v.y) + (v.z + v.w);
        s2 += (v.x * v.x + v.y * v.y) + (v.z * v.z + v.w * v.w);
    }
    #pragma unroll
    for (int off = 32; off >= 1; off >>= 1) {
        s  += __shfl_xor(s, off);
        s2 += __shfl_xor(s2, off);
    }
    __shared__ float r1[4], r2[4];
    const int wid = t >> 6;
    if ((t & 63) == 0) { r1[wid] = s; r2[wid] = s2; }
    __syncthreads();
    if (t == 0) {
        s  = (r1[0] + r1[1]) + (r1[2] + r1[3]);
        s2 = (r2[0] + r2[1]) + (r2[2] + r2[3]);
        const float mean = s * (1.0f / 4096.f);
        const float var = (s2 - 4096.f * mean * mean) * (1.0f / 4095.f);
        cmean[bc] = mean;
        cinv[bc] = rsqrtf(fmaxf(var, 0.f) + EPSV);
    }
}

// =====================================================================================
// compute_O + fused O-pack (hi only). grid: (NS/256, CH/8, 2)
// =====================================================================================
__global__ __launch_bounds__(256) void compute_O_pack(
    const float* __restrict__ Mean, const float* __restrict__ Sec,
    const float* __restrict__ content,
    const float* __restrict__ cmean, const float* __restrict__ cinv,
    u16* __restrict__ Oh)
{
    const int n  = blockIdx.x * 256 + threadIdx.x;
    const int cg = blockIdx.y;
    const int b  = blockIdx.z;
    const size_t KN = (size_t)CH * NS;
    u16 h[8];
    #pragma unroll
    for (int j = 0; j < 8; ++j) {
        const int c = cg * 8 + j;
        const size_t po = (size_t)b * KN + (size_t)c * NS + n;
        const float mn = Mean[po];
        const float sc = Sec[po];
        const float ct = content[po];
        const int bc = b * CH + c;
        const float o = sqrtf(fmaxf(sc - mn * mn, 0.f)) * ((ct - cmean[bc]) * cinv[bc]) + mn;
        h[j] = f2h(o);
    }
    const size_t off = (size_t)b * KN + ((size_t)cg * NS + n) * 8;
    *(uint4*)&Oh[off] = *(const uint4*)h;
}

// =====================================================================================
extern "C" void kernel_launch(void* const* d_in, const int* in_sizes, int n_in,
                              void* d_out, int out_size, void* d_ws, size_t ws_size,
                              hipStream_t stream)
{
    const float* content = (const float*)d_in[0];
    const float* style   = (const float*)d_in[1];
    const float* f_w   = (const float*)d_in[2];
    const float* f_b   = (const float*)d_in[3];
    const float* g_w   = (const float*)d_in[4];
    const float* g_b   = (const float*)d_in[5];
    const float* h_w   = (const float*)d_in[6];
    const float* h_b   = (const float*)d_in[7];
    const float* out_w = (const float*)d_in[8];
    const float* out_b = (const float*)d_in[9];
    float* out = (float*)d_out;

    char* ws = (char*)d_ws;
    size_t off = 0;
    auto alloc = [&](size_t bytes) -> void* {
        void* p = ws + off;
        off = (off + bytes + 255) & ~(size_t)255;
        return p;
    };

    const size_t KN   = (size_t)CH * NS;      // 2,097,152 elements (one batch plane)
    const size_t CHCH = (size_t)CH * CH;
    const long   NSNS = (long)NS * NS;

    // ---- weight packs: hi-only, contiguous [Wh0 Wh1 Wh2 Wh3] ----
    u16* Wh0 = (u16*)alloc(4 * CHCH * 2);
    u16* Whv[4] = { Wh0, Wh0 + CHCH, Wh0 + 2 * CHCH, Wh0 + 3 * CHCH };

    // ---- R2: two time-disjoint layouts:
    //   phase 1 (conv inputs, hi-only):  [Xc_hi | Xs_hi]               (each 2KN)
    //   phase 2 (PV A-packs):            [HvT_hi | Hv2T_hi | Hv2T_lo] (each 2KN)
    u16* R2 = (u16*)alloc(6 * KN * 2);
    u16* Xc_hi = R2;
    u16* Xs_hi = R2 + 2 * KN;
    u16* HvT_hi  = R2;
    u16* Hv2T_hi = R2 + 2 * KN;
    u16* Hv2T_lo = R2 + 4 * KN;

    // ---- R3: [Fqp_hi | Gkp_hi], each 2KN u16; Gkp reused as O pack ----
    u16* Fqp_hi = (u16*)alloc(2 * KN * 2);
    u16* Gkp_hi = (u16*)alloc(2 * KN * 2);
    u16* Op_hi  = Gkp_hi;

    // ---- R5: union: Hv32 fp32 (during convs) -> E16 both batches (67 MB) ----
    char* R5 = (char*)alloc(2 * (size_t)NS * NS * 2);
    float* Hv32 = (float*)(R5 + 4 * KN * 4);   // conv z=4,5 output (dead after pack_hvT)
    u16*   E16  = (u16*)R5;                    // QK output: fp16(exp(s - groupmax)), packed

    // ---- R6: Mean/Sec fp32, contiguous ----
    float* Mean32 = (float*)alloc(2 * KN * 4);
    float* Sec32  = (float*)alloc(2 * KN * 4);

    // ---- small ----
    float* pm    = (float*)alloc(2 * 32 * NS * 4);
    float* ps    = (float*)alloc(2 * 32 * NS * 4);
    float* mxv   = (float*)alloc(2 * NS * 4);
    float* invv  = (float*)alloc(2 * NS * 4);
    float* ctab  = (float*)alloc(2 * 32 * NS * 4);
    float* cmean = (float*)alloc(1024 * 4);
    float* cinv  = (float*)alloc(1024 * 4);
    (void)ws_size; (void)in_sizes; (void)n_in; (void)out_size;

    // ================= pipeline =================
    packA_T<<<dim3(8, 8), 256, 0, stream>>>(f_w,   Whv[0], CH);
    packA_T<<<dim3(8, 8), 256, 0, stream>>>(g_w,   Whv[1], CH);
    packA_T<<<dim3(8, 8), 256, 0, stream>>>(h_w,   Whv[2], CH);
    packA_T<<<dim3(8, 8), 256, 0, stream>>>(out_w, Whv[3], CH);
    packB_k<<<dim3(16, 64, 2), 256, 0, stream>>>(content, Xc_hi, NS, (long)KN, (long)KN);
    packB_k<<<dim3(16, 64, 2), 256, 0, stream>>>(style,   Xs_hi, NS, (long)KN, (long)KN);
    content_stats<<<1024, 256, 0, stream>>>(content, cmean, cinv);

    // ---- merged conv3 (1-term, np=2: Whi*Xhi): z = w*2 + b;
    //      w=0 (f,content)->Fqp hi, w=1 (g,style)->Gkp hi, w=2 (h,style)->Hv32 fp32 ----
    {
        ZTab tb = {};
        const float* bs[3] = { f_b, g_b, h_b };
        for (int z = 0; z < 6; ++z) {
            const int w = z >> 1, b = z & 1;
            tb.aoff[z] = (long)w * CHCH;
            tb.boff[z] = (w == 0 ? 0 : (long)(2 * KN)) + (long)b * KN;
            tb.mode[z] = (w < 2) ? 1 : 0;
            tb.np[z]   = 2;
            tb.ooff[z] = (w < 2) ? ((long)w * 2 * KN + (long)b * KN)   // u16 elems from Fqp_hi
                                 : ((long)4 * KN + (long)b * KN);      // fp32 elems from R5
            tb.bias[z] = bs[w];
        }
        gemm_split<2, false, false, false><<<dim3(32, 4, 6), 256, 0, stream>>>(
            Wh0, nullptr, Xc_hi, nullptr,
            (float*)R5, Fqp_hi, nullptr, nullptr, nullptr, CH, NS, CH, tb);
    }

    // quantized-moments Hv packs (overwrites R2 phase-1; Xc/Xs dead)
    pack_hvT<<<dim3(64, 8, 2), 256, 0, stream>>>(Hv32, HvT_hi, Hv2T_hi, Hv2T_lo);

    // ---- merged QK (1-term, np=2, z=2): E16 = fp16(exp(S - 128-group max)), packed;
    //      fused per-128-group col-stats (cross-wave combine in epilogue) ----
    {
        ZTab tq = {};
        for (int z = 0; z < 2; ++z) {
            tq.aoff[z] = (long)z * KN;     // Gk batch
            tq.boff[z] = (long)z * KN;     // Fq batch
            tq.ooff[z] = (long)z * NSNS;   // E16 batch (u16 elems)
            tq.np[z]   = 2;
        }
        gemm_split<2, false, true, false><<<dim3(32, 32, 2), 256, 0, stream>>>(
            Gkp_hi, nullptr, Fqp_hi, nullptr,
            nullptr, E16, pm, ps, nullptr, NS, NS, CH, tq);
    }
    colstats_comb32<<<dim3(16, 2), 256, 0, stream>>>(pm, ps, mxv, invv);
    scale_c<<<dim3(16, 32, 2), 256, 0, stream>>>(pm, mxv, invv, ctab);

    // ---- merged PV (GS): z=0,1 -> Mean (A=HvT_hi, np=2); z=2,3 -> Sec (np=3);
    //      B = E16, per-128-group fragment rescale by ctab ----
    {
        ZTab tp = {};
        for (int z = 0; z < 4; ++z) {
            const int sec = (z >> 1), b = z & 1;
            tp.aoff[z] = (long)sec * 2 * KN + (long)b * KN;   // Ahi base R2; Alo base R2+2KN
            tp.boff[z] = (long)b * NSNS;
            tp.ooff[z] = (long)sec * 2 * KN + (long)b * KN;   // Mean32 / Sec32
            tp.coff[z] = (long)b * 32 * NS;
            tp.np[z]   = sec ? 3 : 2;
        }
        gemm_split<3, false, false, true><<<dim3(32, 4, 4), 256, 0, stream>>>(
            R2, R2 + 2 * KN, E16, nullptr,
            Mean32, nullptr, nullptr, nullptr, ctab, CH, NS, NS, tp);
    }

    // O + fused pack (fp16 hi only)
    compute_O_pack<<<dim3(16, 64, 2), 256, 0, stream>>>(
        Mean32, Sec32, content, cmean, cinv, Op_hi);

    // ---- out conv (1-term, np=2: Whi*O_hi): bias + residual(content) -> d_out ----
    {
        ZTab tf = {};
        for (int z = 0; z < 2; ++z) {
            tf.ooff[z] = (long)z * KN;
            tf.boff[z] = (long)z * KN;
            tf.np[z]   = 2;
            tf.bias[z] = out_b;
        }
        gemm_split<2, true, false, false><<<dim3(32, 4, 2), 256, 0, stream>>>(
            Whv[3], nullptr, Op_hi, content,
            out, nullptr, nullptr, nullptr, nullptr, CH, NS, CH, tf);
    }
}

// Round 13
// 234.444 us; speedup vs baseline: 2.2466x; 1.0474x over previous
//
#include <hip/hip_runtime.h>
#include <math.h>

#define NS 4096
#define CH 512
#define EPSV 1e-5f

typedef __attribute__((ext_vector_type(8))) _Float16 f16x8;  // 8 x fp16 MFMA operand
typedef __attribute__((ext_vector_type(4))) float f32x4;     // MFMA accumulator
typedef unsigned short u16;

// ---------- fp16 helpers (RNE via cast) ----------
__device__ __forceinline__ u16 f2h(float x) {
    _Float16 h = (_Float16)x;
    return __builtin_bit_cast(unsigned short, h);
}
__device__ __forceinline__ float h2f(u16 b) {
    return (float)__builtin_bit_cast(_Float16, b);
}

// ---------- async global->LDS, 16B per lane ----------
__device__ __forceinline__ void gload16(const void* g, void* l) {
    __builtin_amdgcn_global_load_lds((const __attribute__((address_space(1))) unsigned*)g,
                                     (__attribute__((address_space(3))) unsigned*)l, 16, 0, 0);
}

// per-z dispatch table (up to 8 z-slices). np[z] = planes staged (prefix of
// [Ahi, Bhi, Alo]):
//   np=2 -> out = Ahi*Bhi           (1 MFMA term)
//   np=3 -> out = (Ahi+Alo)*Bhi     (2 terms)
// mode: 0 = fp32 out (+bias, +resid), 1 = packed fp16 HI-ONLY out [K/8][N][8].
// coff: per-z offset (floats) into the group-scale table c (GS kernels only).
struct ZTab {
    long aoff[8];
    long boff[8];
    long ooff[8];
    long coff[8];
    int  mode[8];
    int  np[8];
    const float* bias[8];
};

struct PA4 { const float* w[4]; };
struct PB2 { const float* x[2]; };

// =====================================================================================
// kloop<NPZ,GS>: fully-unrolled compile-time staging + MFMA pipeline, 2-phase dbuf.
// GS (PV): B = E16 = fp16(exp(s - groupmax_g)). Per 128-wide k-group g, the B
// fragment (one column n per lane) is scaled by ch = fp16(c[g][n]) BEFORE the MFMA
// (v_pk_mul_f16, VALU pipe) -- identical math to scaling the partial sum, zero
// extra accumulators (round-11 spill lesson).
// =====================================================================================
template<int NPZ, bool GS>
__device__ __forceinline__ void kloop(
    const u16* __restrict__ pAhi, const u16* __restrict__ pAlo,
    const u16* __restrict__ pBhi,
    u16* smem, int smemStride,
    int Mw, int Nw, int K, int m0, int n0,
    int wid, int lane, int lk, int lm, int wm, int wn,
    const float* __restrict__ cbase,
    f32x4 (&acc)[4][4])
{
    auto stage = [&](int buf, int ks) {
        const int kp0 = ks << 2;
        #pragma unroll
        for (int i = 0; i < 2 * NPZ; ++i) {
            const int q = i * 4 + wid;                 // wave-uniform
            const int b = q >> 3;                      // plane id (compile-time per i)
            const int p = (q & 7) >> 1;                // k-plane
            const int w = ((q & 1) << 6) + lane;       // width index 0..127
            const u16* src;
            if (b == 0)      src = pAhi + ((size_t)(kp0 + p) * Mw + m0 + w) * 8;
            else if (b == 1) src = pBhi + ((size_t)(kp0 + p) * Nw + n0 + w) * 8;
            else             src = pAlo + ((size_t)(kp0 + p) * Mw + m0 + w) * 8;
            gload16(src, &smem[(size_t)buf * smemStride + (size_t)(((b * 4 + p) * 128) + w) * 8]);
        }
    };

    const int nK = K >> 5;
    stage(0, 0);
    __syncthreads();                 // drains vmcnt(0): buf0 ready
    int cur = 0;
    _Float16 ch[4] = {};
    for (int ks = 0; ks < nK; ++ks) {
        if (GS && (ks & 3) == 0) {
            const int g = ks >> 2;
            #pragma unroll
            for (int j = 0; j < 4; ++j)
                ch[j] = (_Float16)cbase[(size_t)g * NS + n0 + wn * 64 + j * 16 + lm];
        }
        if (ks + 1 < nK) stage(cur ^ 1, ks + 1);   // prefetch next tile during MFMA
        const u16* sm = smem + (size_t)cur * smemStride;
        f16x8 ah[4], bh[4], al[4];
        #pragma unroll
        for (int f = 0; f < 4; ++f) {
            ah[f] = *(const f16x8*)&sm[((0 * 4 + lk) * 128 + wm * 64 + f * 16 + lm) * 8];
            bh[f] = *(const f16x8*)&sm[((1 * 4 + lk) * 128 + wn * 64 + f * 16 + lm) * 8];
            if (GS) bh[f] = bh[f] * ch[f];          // splat scalar, v_pk_mul_f16
            if (NPZ == 3)
                al[f] = *(const f16x8*)&sm[((2 * 4 + lk) * 128 + wm * 64 + f * 16 + lm) * 8];
        }
        #pragma unroll
        for (int i = 0; i < 4; ++i)
            #pragma unroll
            for (int j = 0; j < 4; ++j) {
                acc[i][j] = __builtin_amdgcn_mfma_f32_16x16x32_f16(ah[i], bh[j], acc[i][j], 0, 0, 0);
                if (NPZ == 3)
                    acc[i][j] = __builtin_amdgcn_mfma_f32_16x16x32_f16(al[i], bh[j], acc[i][j], 0, 0, 0);
            }
        __syncthreads();             // prefetched buffer complete, reads done
        cur ^= 1;
    }
}

// =====================================================================================
// Split-fp16 GEMM:  out[m][n] = sum_k A[k][m] * B[k][n]
// Packed operand layout: element (k, x) at ((k>>3)*W + x)*8 + (k&7)
// Tile 128x128, BK=32, 4 waves (2x2), per-wave 64x64 via 4x4 frags of 16x16x32.
// COLST (QK): cross-wave 128-row-group softmax stats (max, sum(exp)) + stores
//   E16 = fp16(exp(acc - groupmax)) in packed layout.
// GS (PV): B = E16, per-128-group fragment rescale by c[g][n] (see kloop).
// =====================================================================================
template<int NP, bool RESID, bool COLST, bool GS>
__global__ __launch_bounds__(256, (NP == 2 ? 4 : 3)) void gemm_split(
    const u16* __restrict__ Ahi, const u16* __restrict__ Alo,
    const u16* __restrict__ Bhi,
    const float* __restrict__ resid,
    float* __restrict__ outF, u16* __restrict__ outH,
    float* __restrict__ pmg, float* __restrict__ psg,
    const float* __restrict__ cb,
    int Mw, int Nw, int K, ZTab tab)
{
    __shared__ u16 smem[2][NP * 4 * 128 * 8];   // 2 x (NP*8KB) double buffer
    const int t = threadIdx.x;
    const int lane = t & 63;
    const int wid = t >> 6;
    const int wm = wid >> 1, wn = wid & 1;
    const int lk = lane >> 4, lm = lane & 15;
    const int m0 = blockIdx.y * 128, n0 = blockIdx.x * 128;
    const int z = blockIdx.z;
    const int npz = tab.np[z];
    const u16* pAhi = Ahi + tab.aoff[z];
    const u16* pAlo = Alo + tab.aoff[z];
    const u16* pBhi = Bhi + tab.boff[z];
    const float* cbase = GS ? (cb + tab.coff[z]) : nullptr;

    f32x4 acc[4][4] = {};
    const int smemStride = NP * 4 * 128 * 8;

    if constexpr (NP == 2) {
        kloop<2, GS>(pAhi, pAlo, pBhi, &smem[0][0], smemStride,
                     Mw, Nw, K, m0, n0, wid, lane, lk, lm, wm, wn, cbase, acc);
    } else {
        if (npz == 2)
            kloop<2, GS>(pAhi, pAlo, pBhi, &smem[0][0], smemStride,
                         Mw, Nw, K, m0, n0, wid, lane, lk, lm, wm, wn, cbase, acc);
        else
            kloop<3, GS>(pAhi, pAlo, pBhi, &smem[0][0], smemStride,
                         Mw, Nw, K, m0, n0, wid, lane, lk, lm, wm, wn, cbase, acc);
    }

    // ---- epilogue: C/D layout col = lane&15, row = (lane>>4)*4 + reg ----
    const float* bp = tab.bias[z];
    if (COLST) {
        // per-wave 64-row stats, combined across wm into 128-row groups via LDS.
        float* smx = (float*)&smem[0][0];          // [2][128]
        float* ssm = smx + 256;
        #pragma unroll
        for (int j = 0; j < 4; ++j) {
            float mx = -3.0e38f;
            #pragma unroll
            for (int i = 0; i < 4; ++i)
                #pragma unroll
                for (int r = 0; r < 4; ++r)
                    mx = fmaxf(mx, acc[i][j][r]);
            mx = fmaxf(mx, __shfl_xor(mx, 16));
            mx = fmaxf(mx, __shfl_xor(mx, 32));
            float sum = 0.f;
            #pragma unroll
            for (int i = 0; i < 4; ++i)
                #pragma unroll
                for (int r = 0; r < 4; ++r)
                    sum += __expf(acc[i][j][r] - mx);
            sum += __shfl_xor(sum, 16);
            sum += __shfl_xor(sum, 32);
            if (lk == 0) {
                const int nloc = wn * 64 + j * 16 + lm;
                smx[wm * 128 + nloc] = mx;
                ssm[wm * 128 + nloc] = sum;
            }
        }
        __syncthreads();
        float mxc[4];
        #pragma unroll
        for (int j = 0; j < 4; ++j) {
            const int nloc = wn * 64 + j * 16 + lm;
            const float m0v = smx[nloc], m1v = smx[128 + nloc];
            const float mc = fmaxf(m0v, m1v);
            mxc[j] = mc;
            if (wm == 0 && lk == 0) {
                const float sc = ssm[nloc] * __expf(m0v - mc) + ssm[128 + nloc] * __expf(m1v - mc);
                const int n = n0 + nloc;
                const size_t gi = ((size_t)z * 32 + (m0 >> 7)) * NS + n;
                pmg[gi] = mc;
                psg[gi] = sc;
            }
        }
        // E16 store, packed layout (k=m): ((m>>3)*Nw + n)*8 + (m&7)
        u16* ph = outH + tab.ooff[z];
        #pragma unroll
        for (int i = 0; i < 4; ++i) {
            const long rg = (long)((m0 + wm * 64) >> 3) + i * 2 + (lk >> 1);
            const int sub = (lk & 1) * 4;
            #pragma unroll
            for (int j = 0; j < 4; ++j) {
                const int n = n0 + wn * 64 + j * 16 + lm;
                const long idx = (rg * Nw + n) * 8 + sub;
                u16 h[4];
                #pragma unroll
                for (int r = 0; r < 4; ++r)
                    h[r] = f2h(__expf(acc[i][j][r] - mxc[j]));
                *(ushort4*)&ph[idx] = make_ushort4(h[0], h[1], h[2], h[3]);
            }
        }
    } else if (tab.mode[z] == 0) {
        float* pout = outF + tab.ooff[z];
        #pragma unroll
        for (int i = 0; i < 4; ++i) {
            #pragma unroll
            for (int r = 0; r < 4; ++r) {
                const int m = m0 + wm * 64 + i * 16 + lk * 4 + r;
                const float bv = bp ? bp[m] : 0.f;
                const size_t ro = (size_t)m * Nw + n0 + wn * 64 + lm;
                #pragma unroll
                for (int j = 0; j < 4; ++j) {
                    float v = acc[i][j][r] + bv;
                    if (RESID) v += resid[tab.ooff[z] + ro + j * 16];
                    pout[ro + j * 16] = v;
                }
            }
        }
    } else {
        // packed fp16 hi-only out
        u16* ph = outH + tab.ooff[z];
        #pragma unroll
        for (int i = 0; i < 4; ++i) {
            float bv[4];
            #pragma unroll
            for (int r = 0; r < 4; ++r) {
                const int m = m0 + wm * 64 + i * 16 + lk * 4 + r;
                bv[r] = bp ? bp[m] : 0.f;
            }
            const long rg = (long)((m0 + wm * 64) >> 3) + i * 2 + (lk >> 1);
            const int sub = (lk & 1) * 4;
            #pragma unroll
            for (int j = 0; j < 4; ++j) {
                const int n = n0 + wn * 64 + j * 16 + lm;
                const long idx = (rg * Nw + n) * 8 + sub;
                u16 h[4];
                #pragma unroll
                for (int r = 0; r < 4; ++r)
                    h[r] = f2h(acc[i][j][r] + bv[r]);
                *(ushort4*)&ph[idx] = make_ushort4(h[0], h[1], h[2], h[3]);
            }
        }
    }
}

// =====================================================================================
// packB4: fp32 inputs {content,style} x {b0,b1} -> fp16 hi packed [K/8][N][8],
// contiguous output [Xc_b0 | Xc_b1 | Xs_b0 | Xs_b1]. grid: (16, 64, 4)
// =====================================================================================
__global__ __launch_bounds__(256) void packB4(PB2 xs, u16* __restrict__ Hi)
{
    const int n = blockIdx.x * 256 + threadIdx.x;
    const int p = blockIdx.y;
    const int z = blockIdx.z;
    const size_t KN = (size_t)CH * NS;
    const float* Xp = xs.x[z >> 1] + (size_t)(z & 1) * KN + ((size_t)p * 8) * NS + n;
    u16 hi[8];
    #pragma unroll
    for (int j = 0; j < 8; ++j)
        hi[j] = f2h(Xp[(size_t)j * NS]);
    const size_t o = (size_t)z * KN + ((size_t)p * NS + n) * 8;
    *(uint4*)&Hi[o] = *(const uint4*)hi;
}

// =====================================================================================
// packA4: 4 weights [512][512] fp32 -> transposed packed [K/8][512][8], HI only.
// grid: (8, 8, 4)
// =====================================================================================
__global__ __launch_bounds__(256) void packA4(PA4 ws, u16* __restrict__ Hi)
{
    __shared__ float tile[64][65];
    const int t = threadIdx.x;
    const int k0 = blockIdx.x * 64, m0 = blockIdx.y * 64;
    const float* W = ws.w[blockIdx.z];
    u16* H = Hi + (size_t)blockIdx.z * CH * CH;
    const int kk = t & 63, mb = t >> 6;
    #pragma unroll
    for (int it = 0; it < 16; ++it) {
        int mm = mb + it * 4;
        tile[mm][kk] = W[(size_t)(m0 + mm) * CH + k0 + kk];
    }
    __syncthreads();
    #pragma unroll
    for (int cc = 0; cc < 2; ++cc) {
        int c = t + cc * 256;
        int kp = c >> 6, m = c & 63;
        u16 hi[8];
        #pragma unroll
        for (int j = 0; j < 8; ++j)
            hi[j] = f2h(tile[m][kp * 8 + j]);
        size_t o = ((size_t)(k0 / 8 + kp) * CH + m0 + m) * 8;
        *(uint4*)&H[o] = *(const uint4*)hi;
    }
}

// =====================================================================================
// pack_hvT (quantized-moments form): Hv fp32 [C][N] ->
//   H1h = fp16(hv); H2h/H2l = hi/lo split of (fp16(hv))^2 (exact in fp32).
// grid: (N/64, C/64, 2=batch)
// =====================================================================================
__global__ __launch_bounds__(256) void pack_hvT(const float* __restrict__ Hv,
    u16* __restrict__ H1h, u16* __restrict__ H2h, u16* __restrict__ H2l)
{
    __shared__ float tile[64][65];
    const int t = threadIdx.x;
    const int s0 = blockIdx.x * 64, c0 = blockIdx.y * 64;
    const int z = blockIdx.z;
    const float* src = Hv + (size_t)z * CH * NS;
    const int ss = t & 63, cb = t >> 6;
    #pragma unroll
    for (int it = 0; it < 16; ++it) {
        int cc = cb + it * 4;
        tile[cc][ss] = src[(size_t)(c0 + cc) * NS + s0 + ss];
    }
    __syncthreads();
    const size_t zb = (size_t)z * NS * CH;
    #pragma unroll
    for (int cc2 = 0; cc2 < 2; ++cc2) {
        int c = t + cc2 * 256;
        int sp = c >> 6, cm = c & 63;
        u16 h1[8], h2[8], l2[8];
        #pragma unroll
        for (int j = 0; j < 8; ++j) {
            float v = tile[cm][sp * 8 + j];
            u16 a = f2h(v);
            h1[j] = a;
            float q = h2f(a);
            float q2 = q * q;
            u16 b = f2h(q2);
            h2[j] = b;
            l2[j] = f2h(q2 - h2f(b));
        }
        size_t o = zb + ((size_t)(s0 / 8 + sp) * CH + c0 + cm) * 8;
        *(uint4*)&H1h[o] = *(const uint4*)h1;
        *(uint4*)&H2h[o] = *(const uint4*)h2;
        *(uint4*)&H2l[o] = *(const uint4*)l2;
    }
}

// =====================================================================================
// colstats_comb32 + fused scale_c: combine 32 row-group partials -> column max +
// 1/sum, then write ctab[z][g][n] = exp(pm - max) * inv. grid (16, 2)
// =====================================================================================
__global__ __launch_bounds__(256) void colstats_comb32(const float* __restrict__ pm,
    const float* __restrict__ ps, float* __restrict__ ctab)
{
    const int n = blockIdx.x * 256 + threadIdx.x;
    const int z = blockIdx.y;
    float m = -3.0e38f, s = 0.f;
    #pragma unroll 8
    for (int g = 0; g < 32; ++g) {
        float gm = pm[((size_t)z * 32 + g) * NS + n], gs = ps[((size_t)z * 32 + g) * NS + n];
        float nm = fmaxf(m, gm);
        s = s * __expf(m - nm) + gs * __expf(gm - nm);
        m = nm;
    }
    const float inv = 1.f / s;
    #pragma unroll 8
    for (int g = 0; g < 32; ++g) {
        const size_t gi = ((size_t)z * 32 + g) * NS + n;
        ctab[gi] = __expf(pm[gi] - m) * inv;
    }
}

// ================= per-(b,c) content stats =================
__global__ __launch_bounds__(256) void content_stats(const float* __restrict__ content,
                                                     float* __restrict__ cmean,
                                                     float* __restrict__ cinv)
{
    const int bc = blockIdx.x;
    const float4* p = (const float4*)(content + (size_t)bc * NS);
    const int t = threadIdx.x;
    float s = 0.f, s2 = 0.f;
    #pragma unroll
    for (int j = 0; j < 4; ++j) {
        float4 v = p[t + j * 256];
        s  += (v.x + v.y) + (v.z + v.w);
        s2 += (v.x * v.x + v.y * v.y) + (v.z * v.z + v.w * v.w);
    }
    #pragma unroll
    for (int off = 32; off >= 1; off >>= 1) {
        s  += __shfl_xor(s, off);
        s2 += __shfl_xor(s2, off);
    }
    __shared__ float r1[4], r2[4];
    const int wid = t >> 6;
    if ((t & 63) == 0) { r1[wid] = s; r2[wid] = s2; }
    __syncthreads();
    if (t == 0) {
        s  = (r1[0] + r1[1]) + (r1[2] + r1[3]);
        s2 = (r2[0] + r2[1]) + (r2[2] + r2[3]);
        const float mean = s * (1.0f / 4096.f);
        const float var = (s2 - 4096.f * mean * mean) * (1.0f / 4095.f);
        cmean[bc] = mean;
        cinv[bc] = rsqrtf(fmaxf(var, 0.f) + EPSV);
    }
}

// =====================================================================================
// compute_O + combine split-K partials + fused O-pack (hi only).
// MS layout (floats): [Mean_p0 4KN? no: p*4KN + sec*2KN + b*KN], see launch.
// mn = Mean_p0 + Mean_p1; sc = Sec_p0 + Sec_p1. grid: (NS/256, CH/8, 2)
// =====================================================================================
__global__ __launch_bounds__(256) void compute_O_pack(
    const float* __restrict__ MS,
    const float* __restrict__ content,
    const float* __restrict__ cmean, const float* __restrict__ cinv,
    u16* __restrict__ Oh)
{
    const int n  = blockIdx.x * 256 + threadIdx.x;
    const int cg = blockIdx.y;
    const int b  = blockIdx.z;
    const size_t KN = (size_t)CH * NS;
    u16 h[8];
    #pragma unroll
    for (int j = 0; j < 8; ++j) {
        const int c = cg * 8 + j;
        const size_t po = (size_t)b * KN + (size_t)c * NS + n;
        const float mn = MS[po] + MS[po + 4 * KN];
        const float sc = MS[po + 2 * KN] + MS[po + 6 * KN];
        const float ct = content[po];
        const int bc = b * CH + c;
        const float o = sqrtf(fmaxf(sc - mn * mn, 0.f)) * ((ct - cmean[bc]) * cinv[bc]) + mn;
        h[j] = f2h(o);
    }
    const size_t off = (size_t)b * KN + ((size_t)cg * NS + n) * 8;
    *(uint4*)&Oh[off] = *(const uint4*)h;
}

// =====================================================================================
extern "C" void kernel_launch(void* const* d_in, const int* in_sizes, int n_in,
                              void* d_out, int out_size, void* d_ws, size_t ws_size,
                              hipStream_t stream)
{
    const float* content = (const float*)d_in[0];
    const float* style   = (const float*)d_in[1];
    const float* f_w   = (const float*)d_in[2];
    const float* f_b   = (const float*)d_in[3];
    const float* g_w   = (const float*)d_in[4];
    const float* g_b   = (const float*)d_in[5];
    const float* h_w   = (const float*)d_in[6];
    const float* h_b   = (const float*)d_in[7];
    const float* out_w = (const float*)d_in[8];
    const float* out_b = (const float*)d_in[9];
    float* out = (float*)d_out;

    char* ws = (char*)d_ws;
    size_t off = 0;
    auto alloc = [&](size_t bytes) -> void* {
        void* p = ws + off;
        off = (off + bytes + 255) & ~(size_t)255;
        return p;
    };

    const size_t KN   = (size_t)CH * NS;      // 2,097,152 elements (one batch plane)
    const size_t CHCH = (size_t)CH * CH;
    const long   NSNS = (long)NS * NS;

    // ---- weight packs: hi-only, contiguous [Wh0 Wh1 Wh2 Wh3] ----
    u16* Wh0 = (u16*)alloc(4 * CHCH * 2);

    // ---- R2: two time-disjoint layouts:
    //   phase 1 (conv inputs, hi-only):  [Xc_hi | Xs_hi]               (each 2KN)
    //   phase 2 (PV A-packs):            [HvT_hi | Hv2T_hi | Hv2T_lo] (each 2KN)
    u16* R2 = (u16*)alloc(6 * KN * 2);
    u16* Xc_hi = R2;
    u16* HvT_hi  = R2;
    u16* Hv2T_hi = R2 + 2 * KN;
    u16* Hv2T_lo = R2 + 4 * KN;
    (void)HvT_hi;

    // ---- R3: [Fqp_hi | Gkp_hi], each 2KN u16; Gkp reused as O pack ----
    u16* Fqp_hi = (u16*)alloc(2 * KN * 2);
    u16* Gkp_hi = (u16*)alloc(2 * KN * 2);
    u16* Op_hi  = Gkp_hi;

    // ---- R5: union: Hv32 fp32 (during convs) -> E16 both batches (67 MB) ----
    char* R5 = (char*)alloc(2 * (size_t)NS * NS * 2);
    float* Hv32 = (float*)(R5 + 4 * KN * 4);   // conv z=4,5 output (dead after pack_hvT)
    u16*   E16  = (u16*)R5;                    // QK output: fp16(exp(s - groupmax)), packed

    // ---- R6: split-K PV partials: [p=0: Mean(2KN) Sec(2KN) | p=1: Mean Sec] ----
    float* MS = (float*)alloc(8 * KN * 4);

    // ---- small ----
    float* pm    = (float*)alloc(2 * 32 * NS * 4);
    float* ps    = (float*)alloc(2 * 32 * NS * 4);
    float* ctab  = (float*)alloc(2 * 32 * NS * 4);
    float* cmean = (float*)alloc(1024 * 4);
    float* cinv  = (float*)alloc(1024 * 4);
    (void)ws_size; (void)in_sizes; (void)n_in; (void)out_size;

    // ================= pipeline =================
    {
        PA4 pa = { { f_w, g_w, h_w, out_w } };
        packA4<<<dim3(8, 8, 4), 256, 0, stream>>>(pa, Wh0);
        PB2 pb = { { content, style } };
        packB4<<<dim3(16, 64, 4), 256, 0, stream>>>(pb, Xc_hi);
    }
    content_stats<<<1024, 256, 0, stream>>>(content, cmean, cinv);

    // ---- merged conv3 (1-term, np=2: Whi*Xhi): z = w*2 + b;
    //      w=0 (f,content)->Fqp hi, w=1 (g,style)->Gkp hi, w=2 (h,style)->Hv32 fp32 ----
    {
        ZTab tb = {};
        const float* bs[3] = { f_b, g_b, h_b };
        for (int z = 0; z < 6; ++z) {
            const int w = z >> 1, b = z & 1;
            tb.aoff[z] = (long)w * CHCH;
            tb.boff[z] = (w == 0 ? 0 : (long)(2 * KN)) + (long)b * KN;
            tb.mode[z] = (w < 2) ? 1 : 0;
            tb.np[z]   = 2;
            tb.ooff[z] = (w < 2) ? ((long)w * 2 * KN + (long)b * KN)   // u16 elems from Fqp_hi
                                 : ((long)4 * KN + (long)b * KN);      // fp32 elems from R5
            tb.bias[z] = bs[w];
        }
        gemm_split<2, false, false, false><<<dim3(32, 4, 6), 256, 0, stream>>>(
            Wh0, nullptr, Xc_hi, nullptr,
            (float*)R5, Fqp_hi, nullptr, nullptr, nullptr, CH, NS, CH, tb);
    }

    // quantized-moments Hv packs (overwrites R2 phase-1; Xc/Xs dead)
    pack_hvT<<<dim3(64, 8, 2), 256, 0, stream>>>(Hv32, R2, Hv2T_hi, Hv2T_lo);

    // ---- merged QK (1-term, np=2, z=2): E16 = fp16(exp(S - 128-group max)), packed;
    //      fused per-128-group col-stats (cross-wave combine in epilogue) ----
    {
        ZTab tq = {};
        for (int z = 0; z < 2; ++z) {
            tq.aoff[z] = (long)z * KN;     // Gk batch
            tq.boff[z] = (long)z * KN;     // Fq batch
            tq.ooff[z] = (long)z * NSNS;   // E16 batch (u16 elems)
            tq.np[z]   = 2;
        }
        gemm_split<2, false, true, false><<<dim3(32, 32, 2), 256, 0, stream>>>(
            Gkp_hi, nullptr, Fqp_hi, nullptr,
            nullptr, E16, pm, ps, nullptr, NS, NS, CH, tq);
    }
    colstats_comb32<<<dim3(16, 2), 256, 0, stream>>>(pm, ps, ctab);

    // ---- merged split-K PV (GS): z = p*4 + sec*2 + b; K = NS/2 per slice.
    //      sec=0 -> Mean (A=HvT_hi, np=2); sec=1 -> Sec (A=Hv2T hi/lo, np=3).
    //      p selects s-half; partials to MS[p][sec][b]. 1024 blocks -> 3 res/CU. ----
    {
        ZTab tp = {};
        for (int z = 0; z < 8; ++z) {
            const int p = z >> 2, sec = (z >> 1) & 1, b = z & 1;
            tp.aoff[z] = (long)sec * 2 * KN + (long)b * KN + (long)p * (KN / 2);
            tp.boff[z] = (long)b * NSNS + (long)p * (NSNS / 2);
            tp.ooff[z] = (long)p * 4 * KN + (long)sec * 2 * KN + (long)b * KN;
            tp.coff[z] = (long)b * 32 * NS + (long)p * 16 * NS;
            tp.np[z]   = sec ? 3 : 2;
        }
        gemm_split<3, false, false, true><<<dim3(32, 4, 8), 256, 0, stream>>>(
            R2, R2 + 2 * KN, E16, nullptr,
            MS, nullptr, nullptr, nullptr, ctab, CH, NS, NS / 2, tp);
    }

    // O + split-K combine + fused pack (fp16 hi only)
    compute_O_pack<<<dim3(16, 64, 2), 256, 0, stream>>>(
        MS, content, cmean, cinv, Op_hi);

    // ---- out conv (1-term, np=2: Whi*O_hi): bias + residual(content) -> d_out ----
    {
        ZTab tf = {};
        for (int z = 0; z < 2; ++z) {
            tf.aoff[z] = (long)3 * CHCH;
            tf.ooff[z] = (long)z * KN;
            tf.boff[z] = (long)z * KN;
            tf.np[z]   = 2;
            tf.bias[z] = out_b;
        }
        gemm_split<2, true, false, false><<<dim3(32, 4, 2), 256, 0, stream>>>(
            Wh0, nullptr, Op_hi, content,
            out, nullptr, nullptr, nullptr, nullptr, CH, NS, CH, tf);
    }
}

// Round 14
// 212.168 us; speedup vs baseline: 2.4825x; 1.1050x over previous
//
#include <hip/hip_runtime.h>
#include <math.h>

#define NS 4096
#define CH 512
#define EPSV 1e-5f

typedef __attribute__((ext_vector_type(8))) _Float16 f16x8;  // 8 x fp16 MFMA operand
typedef __attribute__((ext_vector_type(4))) float f32x4;     // MFMA accumulator
typedef unsigned short u16;

// ---------- fp16 helpers (RNE via cast) ----------
__device__ __forceinline__ u16 f2h(float x) {
    _Float16 h = (_Float16)x;
    return __builtin_bit_cast(unsigned short, h);
}
__device__ __forceinline__ float h2f(u16 b) {
    return (float)__builtin_bit_cast(_Float16, b);
}

// ---------- async global->LDS, 16B per lane ----------
__device__ __forceinline__ void gload16(const void* g, void* l) {
    __builtin_amdgcn_global_load_lds((const __attribute__((address_space(1))) unsigned*)g,
                                     (__attribute__((address_space(3))) unsigned*)l, 16, 0, 0);
}

// per-z dispatch table (up to 8 z-slices). np[z] = planes staged (prefix of
// [Ahi, Bhi, Alo]):
//   np=2 -> out = Ahi*Bhi           (1 MFMA term)
//   np=3 -> out = (Ahi+Alo)*Bhi     (2 terms)
// mode: 0 = fp32 out (+bias, +resid), 1 = packed fp16 HI-ONLY out [K/8][N][8].
// coff: per-z offset (floats) into the group-scale table c (GS/PV kernels).
struct ZTab {
    long aoff[8];
    long boff[8];
    long ooff[8];
    long coff[8];
    int  mode[8];
    int  np[8];
    const float* bias[8];
};

struct PA4 { const float* w[4]; };
struct PB2 { const float* x[2]; };

// =====================================================================================
// kloop<NPZ,GS>: fully-unrolled compile-time staging + MFMA pipeline, 2-phase dbuf.
// GS: B fragment scaled by fp16(c[g][n]) before MFMA (v_pk_mul_f16, VALU pipe).
// =====================================================================================
template<int NPZ, bool GS>
__device__ __forceinline__ void kloop(
    const u16* __restrict__ pAhi, const u16* __restrict__ pAlo,
    const u16* __restrict__ pBhi,
    u16* smem, int smemStride,
    int Mw, int Nw, int K, int m0, int n0,
    int wid, int lane, int lk, int lm, int wm, int wn,
    const float* __restrict__ cbase,
    f32x4 (&acc)[4][4])
{
    auto stage = [&](int buf, int ks) {
        const int kp0 = ks << 2;
        #pragma unroll
        for (int i = 0; i < 2 * NPZ; ++i) {
            const int q = i * 4 + wid;                 // wave-uniform
            const int b = q >> 3;                      // plane id (compile-time per i)
            const int p = (q & 7) >> 1;                // k-plane
            const int w = ((q & 1) << 6) + lane;       // width index 0..127
            const u16* src;
            if (b == 0)      src = pAhi + ((size_t)(kp0 + p) * Mw + m0 + w) * 8;
            else if (b == 1) src = pBhi + ((size_t)(kp0 + p) * Nw + n0 + w) * 8;
            else             src = pAlo + ((size_t)(kp0 + p) * Mw + m0 + w) * 8;
            gload16(src, &smem[(size_t)buf * smemStride + (size_t)(((b * 4 + p) * 128) + w) * 8]);
        }
    };

    const int nK = K >> 5;
    stage(0, 0);
    __syncthreads();                 // drains vmcnt(0): buf0 ready
    int cur = 0;
    _Float16 ch[4] = {};
    for (int ks = 0; ks < nK; ++ks) {
        if (GS && (ks & 3) == 0) {
            const int g = ks >> 2;
            #pragma unroll
            for (int j = 0; j < 4; ++j)
                ch[j] = (_Float16)cbase[(size_t)g * NS + n0 + wn * 64 + j * 16 + lm];
        }
        if (ks + 1 < nK) stage(cur ^ 1, ks + 1);   // prefetch next tile during MFMA
        const u16* sm = smem + (size_t)cur * smemStride;
        f16x8 ah[4], bh[4], al[4];
        #pragma unroll
        for (int f = 0; f < 4; ++f) {
            ah[f] = *(const f16x8*)&sm[((0 * 4 + lk) * 128 + wm * 64 + f * 16 + lm) * 8];
            bh[f] = *(const f16x8*)&sm[((1 * 4 + lk) * 128 + wn * 64 + f * 16 + lm) * 8];
            if (GS) bh[f] = bh[f] * ch[f];          // splat scalar, v_pk_mul_f16
            if (NPZ == 3)
                al[f] = *(const f16x8*)&sm[((2 * 4 + lk) * 128 + wm * 64 + f * 16 + lm) * 8];
        }
        #pragma unroll
        for (int i = 0; i < 4; ++i)
            #pragma unroll
            for (int j = 0; j < 4; ++j) {
                acc[i][j] = __builtin_amdgcn_mfma_f32_16x16x32_f16(ah[i], bh[j], acc[i][j], 0, 0, 0);
                if (NPZ == 3)
                    acc[i][j] = __builtin_amdgcn_mfma_f32_16x16x32_f16(al[i], bh[j], acc[i][j], 0, 0, 0);
            }
        __syncthreads();             // prefetched buffer complete, reads done
        cur ^= 1;
    }
}

// =====================================================================================
// Split-fp16 GEMM (generic: convs, QK, out-conv).
// Packed operand layout: element (k, x) at ((k>>3)*W + x)*8 + (k&7)
// Tile 128x128, BK=32, 4 waves (2x2), per-wave 64x64 via 4x4 frags of 16x16x32.
// COLST (QK): cross-wave 128-row-group softmax stats + E16 = fp16(exp(acc-gmax)).
// =====================================================================================
template<int NP, bool RESID, bool COLST, bool GS>
__global__ __launch_bounds__(256, (NP == 2 ? 4 : 3)) void gemm_split(
    const u16* __restrict__ Ahi, const u16* __restrict__ Alo,
    const u16* __restrict__ Bhi,
    const float* __restrict__ resid,
    float* __restrict__ outF, u16* __restrict__ outH,
    float* __restrict__ pmg, float* __restrict__ psg,
    const float* __restrict__ cb,
    int Mw, int Nw, int K, ZTab tab)
{
    __shared__ u16 smem[2][NP * 4 * 128 * 8];   // 2 x (NP*8KB) double buffer
    const int t = threadIdx.x;
    const int lane = t & 63;
    const int wid = t >> 6;
    const int wm = wid >> 1, wn = wid & 1;
    const int lk = lane >> 4, lm = lane & 15;
    const int m0 = blockIdx.y * 128, n0 = blockIdx.x * 128;
    const int z = blockIdx.z;
    const int npz = tab.np[z];
    const u16* pAhi = Ahi + tab.aoff[z];
    const u16* pAlo = Alo + tab.aoff[z];
    const u16* pBhi = Bhi + tab.boff[z];
    const float* cbase = GS ? (cb + tab.coff[z]) : nullptr;

    f32x4 acc[4][4] = {};
    const int smemStride = NP * 4 * 128 * 8;

    if constexpr (NP == 2) {
        kloop<2, GS>(pAhi, pAlo, pBhi, &smem[0][0], smemStride,
                     Mw, Nw, K, m0, n0, wid, lane, lk, lm, wm, wn, cbase, acc);
    } else {
        if (npz == 2)
            kloop<2, GS>(pAhi, pAlo, pBhi, &smem[0][0], smemStride,
                         Mw, Nw, K, m0, n0, wid, lane, lk, lm, wm, wn, cbase, acc);
        else
            kloop<3, GS>(pAhi, pAlo, pBhi, &smem[0][0], smemStride,
                         Mw, Nw, K, m0, n0, wid, lane, lk, lm, wm, wn, cbase, acc);
    }

    // ---- epilogue: C/D layout col = lane&15, row = (lane>>4)*4 + reg ----
    const float* bp = tab.bias[z];
    if (COLST) {
        // per-wave 64-row stats, combined across wm into 128-row groups via LDS.
        float* smx = (float*)&smem[0][0];          // [2][128]
        float* ssm = smx + 256;
        #pragma unroll
        for (int j = 0; j < 4; ++j) {
            float mx = -3.0e38f;
            #pragma unroll
            for (int i = 0; i < 4; ++i)
                #pragma unroll
                for (int r = 0; r < 4; ++r)
                    mx = fmaxf(mx, acc[i][j][r]);
            mx = fmaxf(mx, __shfl_xor(mx, 16));
            mx = fmaxf(mx, __shfl_xor(mx, 32));
            float sum = 0.f;
            #pragma unroll
            for (int i = 0; i < 4; ++i)
                #pragma unroll
                for (int r = 0; r < 4; ++r)
                    sum += __expf(acc[i][j][r] - mx);
            sum += __shfl_xor(sum, 16);
            sum += __shfl_xor(sum, 32);
            if (lk == 0) {
                const int nloc = wn * 64 + j * 16 + lm;
                smx[wm * 128 + nloc] = mx;
                ssm[wm * 128 + nloc] = sum;
            }
        }
        __syncthreads();
        float mxc[4];
        #pragma unroll
        for (int j = 0; j < 4; ++j) {
            const int nloc = wn * 64 + j * 16 + lm;
            const float m0v = smx[nloc], m1v = smx[128 + nloc];
            const float mc = fmaxf(m0v, m1v);
            mxc[j] = mc;
            if (wm == 0 && lk == 0) {
                const float sc = ssm[nloc] * __expf(m0v - mc) + ssm[128 + nloc] * __expf(m1v - mc);
                const int n = n0 + nloc;
                const size_t gi = ((size_t)z * 32 + (m0 >> 7)) * NS + n;
                pmg[gi] = mc;
                psg[gi] = sc;
            }
        }
        // E16 store, packed layout (k=m): ((m>>3)*Nw + n)*8 + (m&7)
        u16* ph = outH + tab.ooff[z];
        #pragma unroll
        for (int i = 0; i < 4; ++i) {
            const long rg = (long)((m0 + wm * 64) >> 3) + i * 2 + (lk >> 1);
            const int sub = (lk & 1) * 4;
            #pragma unroll
            for (int j = 0; j < 4; ++j) {
                const int n = n0 + wn * 64 + j * 16 + lm;
                const long idx = (rg * Nw + n) * 8 + sub;
                u16 h[4];
                #pragma unroll
                for (int r = 0; r < 4; ++r)
                    h[r] = f2h(__expf(acc[i][j][r] - mxc[j]));
                *(ushort4*)&ph[idx] = make_ushort4(h[0], h[1], h[2], h[3]);
            }
        }
    } else if (tab.mode[z] == 0) {
        float* pout = outF + tab.ooff[z];
        #pragma unroll
        for (int i = 0; i < 4; ++i) {
            #pragma unroll
            for (int r = 0; r < 4; ++r) {
                const int m = m0 + wm * 64 + i * 16 + lk * 4 + r;
                const float bv = bp ? bp[m] : 0.f;
                const size_t ro = (size_t)m * Nw + n0 + wn * 64 + lm;
                #pragma unroll
                for (int j = 0; j < 4; ++j) {
                    float v = acc[i][j][r] + bv;
                    if (RESID) v += resid[tab.ooff[z] + ro + j * 16];
                    pout[ro + j * 16] = v;
                }
            }
        }
    } else {
        // packed fp16 hi-only out
        u16* ph = outH + tab.ooff[z];
        #pragma unroll
        for (int i = 0; i < 4; ++i) {
            float bv[4];
            #pragma unroll
            for (int r = 0; r < 4; ++r) {
                const int m = m0 + wm * 64 + i * 16 + lk * 4 + r;
                bv[r] = bp ? bp[m] : 0.f;
            }
            const long rg = (long)((m0 + wm * 64) >> 3) + i * 2 + (lk >> 1);
            const int sub = (lk & 1) * 4;
            #pragma unroll
            for (int j = 0; j < 4; ++j) {
                const int n = n0 + wn * 64 + j * 16 + lm;
                const long idx = (rg * Nw + n) * 8 + sub;
                u16 h[4];
                #pragma unroll
                for (int r = 0; r < 4; ++r)
                    h[r] = f2h(acc[i][j][r] + bv[r]);
                *(ushort4*)&ph[idx] = make_ushort4(h[0], h[1], h[2], h[3]);
            }
        }
    }
}

// =====================================================================================
// gemm_pv: fused Mean+Sec PV. Planes [A1=HvT_hi, B=E16, A2h=Hv2T_hi, A2l=Hv2T_lo]
// staged per K-step (32 KB/buffer, 2-phase dbuf = 64 KB). One B-tile feeds THREE
// MFMA sets: accM += A1*B';  accS += A2h*B' + A2l*B'   (B' = B * c[g][n], fp16).
// E16 global traffic halves vs separate Mean/Sec slices. z = p*2 + b (split-K x2).
// Outputs fp32 partials: Mean at ooff, Sec at ooff + 2KN.
// =====================================================================================
__global__ __launch_bounds__(256, 2) void gemm_pv(
    const u16* __restrict__ A1, const u16* __restrict__ A2h, const u16* __restrict__ A2l,
    const u16* __restrict__ Bhi,
    float* __restrict__ outF, const float* __restrict__ cb,
    int K, ZTab tab)
{
    __shared__ u16 smem[2][4 * 4 * 128 * 8];   // 2 x 32 KB
    const int t = threadIdx.x;
    const int lane = t & 63;
    const int wid = t >> 6;
    const int wm = wid >> 1, wn = wid & 1;
    const int lk = lane >> 4, lm = lane & 15;
    const int m0 = blockIdx.y * 128, n0 = blockIdx.x * 128;
    const int z = blockIdx.z;
    const u16* pA1  = A1  + tab.aoff[z];
    const u16* pA2h = A2h + tab.aoff[z];
    const u16* pA2l = A2l + tab.aoff[z];
    const u16* pB   = Bhi + tab.boff[z];
    const float* cbase = cb + tab.coff[z];
    const int smemStride = 4 * 4 * 128 * 8;

    auto stage = [&](int buf, int ks) {
        const int kp0 = ks << 2;
        #pragma unroll
        for (int i = 0; i < 8; ++i) {
            const int q = i * 4 + wid;                 // wave-uniform
            const int b = q >> 3;                      // plane id
            const int p = (q & 7) >> 1;
            const int w = ((q & 1) << 6) + lane;
            const u16* src;
            if (b == 0)      src = pA1  + ((size_t)(kp0 + p) * CH + m0 + w) * 8;
            else if (b == 1) src = pB   + ((size_t)(kp0 + p) * NS + n0 + w) * 8;
            else if (b == 2) src = pA2h + ((size_t)(kp0 + p) * CH + m0 + w) * 8;
            else             src = pA2l + ((size_t)(kp0 + p) * CH + m0 + w) * 8;
            gload16(src, &smem[buf][(size_t)(((b * 4 + p) * 128) + w) * 8]);
        }
    };

    f32x4 accM[4][4] = {};
    f32x4 accS[4][4] = {};

    const int nK = K >> 5;
    stage(0, 0);
    __syncthreads();
    int cur = 0;
    _Float16 ch[4] = {};
    for (int ks = 0; ks < nK; ++ks) {
        if ((ks & 3) == 0) {
            const int g = ks >> 2;
            #pragma unroll
            for (int j = 0; j < 4; ++j)
                ch[j] = (_Float16)cbase[(size_t)g * NS + n0 + wn * 64 + j * 16 + lm];
        }
        if (ks + 1 < nK) stage(cur ^ 1, ks + 1);
        const u16* sm = smem[cur];
        f16x8 a1[4], bh[4], a2h[4], a2l[4];
        #pragma unroll
        for (int f = 0; f < 4; ++f) {
            a1[f]  = *(const f16x8*)&sm[((0 * 4 + lk) * 128 + wm * 64 + f * 16 + lm) * 8];
            bh[f]  = *(const f16x8*)&sm[((1 * 4 + lk) * 128 + wn * 64 + f * 16 + lm) * 8];
            bh[f]  = bh[f] * ch[f];
            a2h[f] = *(const f16x8*)&sm[((2 * 4 + lk) * 128 + wm * 64 + f * 16 + lm) * 8];
            a2l[f] = *(const f16x8*)&sm[((3 * 4 + lk) * 128 + wm * 64 + f * 16 + lm) * 8];
        }
        #pragma unroll
        for (int i = 0; i < 4; ++i)
            #pragma unroll
            for (int j = 0; j < 4; ++j) {
                accM[i][j] = __builtin_amdgcn_mfma_f32_16x16x32_f16(a1[i],  bh[j], accM[i][j], 0, 0, 0);
                accS[i][j] = __builtin_amdgcn_mfma_f32_16x16x32_f16(a2h[i], bh[j], accS[i][j], 0, 0, 0);
                accS[i][j] = __builtin_amdgcn_mfma_f32_16x16x32_f16(a2l[i], bh[j], accS[i][j], 0, 0, 0);
            }
        __syncthreads();
        cur ^= 1;
    }

    // epilogue: fp32 partials; Mean at ooff, Sec at ooff + 2KN
    const size_t KN = (size_t)CH * NS;
    float* poutM = outF + tab.ooff[z];
    float* poutS = poutM + 2 * KN;
    #pragma unroll
    for (int i = 0; i < 4; ++i) {
        #pragma unroll
        for (int r = 0; r < 4; ++r) {
            const int m = m0 + wm * 64 + i * 16 + lk * 4 + r;
            const size_t ro = (size_t)m * NS + n0 + wn * 64 + lm;
            #pragma unroll
            for (int j = 0; j < 4; ++j) {
                poutM[ro + j * 16] = accM[i][j][r];
                poutS[ro + j * 16] = accS[i][j][r];
            }
        }
    }
}

// =====================================================================================
// packB4: fp32 inputs {content,style} x {b0,b1} -> fp16 hi packed [K/8][N][8],
// contiguous output [Xc_b0 | Xc_b1 | Xs_b0 | Xs_b1]. grid: (16, 64, 4)
// =====================================================================================
__global__ __launch_bounds__(256) void packB4(PB2 xs, u16* __restrict__ Hi)
{
    const int n = blockIdx.x * 256 + threadIdx.x;
    const int p = blockIdx.y;
    const int z = blockIdx.z;
    const size_t KN = (size_t)CH * NS;
    const float* Xp = xs.x[z >> 1] + (size_t)(z & 1) * KN + ((size_t)p * 8) * NS + n;
    u16 hi[8];
    #pragma unroll
    for (int j = 0; j < 8; ++j)
        hi[j] = f2h(Xp[(size_t)j * NS]);
    const size_t o = (size_t)z * KN + ((size_t)p * NS + n) * 8;
    *(uint4*)&Hi[o] = *(const uint4*)hi;
}

// =====================================================================================
// packA4: 4 weights [512][512] fp32 -> transposed packed [K/8][512][8], HI only.
// grid: (8, 8, 4)
// =====================================================================================
__global__ __launch_bounds__(256) void packA4(PA4 ws, u16* __restrict__ Hi)
{
    __shared__ float tile[64][65];
    const int t = threadIdx.x;
    const int k0 = blockIdx.x * 64, m0 = blockIdx.y * 64;
    const float* W = ws.w[blockIdx.z];
    u16* H = Hi + (size_t)blockIdx.z * CH * CH;
    const int kk = t & 63, mb = t >> 6;
    #pragma unroll
    for (int it = 0; it < 16; ++it) {
        int mm = mb + it * 4;
        tile[mm][kk] = W[(size_t)(m0 + mm) * CH + k0 + kk];
    }
    __syncthreads();
    #pragma unroll
    for (int cc = 0; cc < 2; ++cc) {
        int c = t + cc * 256;
        int kp = c >> 6, m = c & 63;
        u16 hi[8];
        #pragma unroll
        for (int j = 0; j < 8; ++j)
            hi[j] = f2h(tile[m][kp * 8 + j]);
        size_t o = ((size_t)(k0 / 8 + kp) * CH + m0 + m) * 8;
        *(uint4*)&H[o] = *(const uint4*)hi;
    }
}

// =====================================================================================
// pack_hvT (quantized-moments form): Hv fp32 [C][N] ->
//   H1h = fp16(hv); H2h/H2l = hi/lo split of (fp16(hv))^2 (exact in fp32).
// grid: (N/64, C/64, 2=batch)
// =====================================================================================
__global__ __launch_bounds__(256) void pack_hvT(const float* __restrict__ Hv,
    u16* __restrict__ H1h, u16* __restrict__ H2h, u16* __restrict__ H2l)
{
    __shared__ float tile[64][65];
    const int t = threadIdx.x;
    const int s0 = blockIdx.x * 64, c0 = blockIdx.y * 64;
    const int z = blockIdx.z;
    const float* src = Hv + (size_t)z * CH * NS;
    const int ss = t & 63, cb = t >> 6;
    #pragma unroll
    for (int it = 0; it < 16; ++it) {
        int cc = cb + it * 4;
        tile[cc][ss] = src[(size_t)(c0 + cc) * NS + s0 + ss];
    }
    __syncthreads();
    const size_t zb = (size_t)z * NS * CH;
    #pragma unroll
    for (int cc2 = 0; cc2 < 2; ++cc2) {
        int c = t + cc2 * 256;
        int sp = c >> 6, cm = c & 63;
        u16 h1[8], h2[8], l2[8];
        #pragma unroll
        for (int j = 0; j < 8; ++j) {
            float v = tile[cm][sp * 8 + j];
            u16 a = f2h(v);
            h1[j] = a;
            float q = h2f(a);
            float q2 = q * q;
            u16 b = f2h(q2);
            h2[j] = b;
            l2[j] = f2h(q2 - h2f(b));
        }
        size_t o = zb + ((size_t)(s0 / 8 + sp) * CH + c0 + cm) * 8;
        *(uint4*)&H1h[o] = *(const uint4*)h1;
        *(uint4*)&H2h[o] = *(const uint4*)h2;
        *(uint4*)&H2l[o] = *(const uint4*)l2;
    }
}

// =====================================================================================
// colstats_comb32 + fused scale_c: combine 32 row-group partials -> column max +
// 1/sum, then write ctab[z][g][n] = exp(pm - max) * inv. grid (16, 2)
// =====================================================================================
__global__ __launch_bounds__(256) void colstats_comb32(const float* __restrict__ pm,
    const float* __restrict__ ps, float* __restrict__ ctab)
{
    const int n = blockIdx.x * 256 + threadIdx.x;
    const int z = blockIdx.y;
    float m = -3.0e38f, s = 0.f;
    #pragma unroll 8
    for (int g = 0; g < 32; ++g) {
        float gm = pm[((size_t)z * 32 + g) * NS + n], gs = ps[((size_t)z * 32 + g) * NS + n];
        float nm = fmaxf(m, gm);
        s = s * __expf(m - nm) + gs * __expf(gm - nm);
        m = nm;
    }
    const float inv = 1.f / s;
    #pragma unroll 8
    for (int g = 0; g < 32; ++g) {
        const size_t gi = ((size_t)z * 32 + g) * NS + n;
        ctab[gi] = __expf(pm[gi] - m) * inv;
    }
}

// ================= per-(b,c) content stats =================
__global__ __launch_bounds__(256) void content_stats(const float* __restrict__ content,
                                                     float* __restrict__ cmean,
                                                     float* __restrict__ cinv)
{
    const int bc = blockIdx.x;
    const float4* p = (const float4*)(content + (size_t)bc * NS);
    const int t = threadIdx.x;
    float s = 0.f, s2 = 0.f;
    #pragma unroll
    for (int j = 0; j < 4; ++j) {
        float4 v = p[t + j * 256];
        s  += (v.x + v.y) + (v.z + v.w);
        s2 += (v.x * v.x + v.y * v.y) + (v.z * v.z + v.w * v.w);
    }
    #pragma unroll
    for (int off = 32; off >= 1; off >>= 1) {
        s  += __shfl_xor(s, off);
        s2 += __shfl_xor(s2, off);
    }
    __shared__ float r1[4], r2[4];
    const int wid = t >> 6;
    if ((t & 63) == 0) { r1[wid] = s; r2[wid] = s2; }
    __syncthreads();
    if (t == 0) {
        s  = (r1[0] + r1[1]) + (r1[2] + r1[3]);
        s2 = (r2[0] + r2[1]) + (r2[2] + r2[3]);
        const float mean = s * (1.0f / 4096.f);
        const float var = (s2 - 4096.f * mean * mean) * (1.0f / 4095.f);
        cmean[bc] = mean;
        cinv[bc] = rsqrtf(fmaxf(var, 0.f) + EPSV);
    }
}

// =====================================================================================
// compute_O + combine split-K partials + fused O-pack (hi only).
// MS layout (floats): p*4KN + sec*2KN + b*KN. grid: (NS/256, CH/8, 2)
// =====================================================================================
__global__ __launch_bounds__(256) void compute_O_pack(
    const float* __restrict__ MS,
    const float* __restrict__ content,
    const float* __restrict__ cmean, const float* __restrict__ cinv,
    u16* __restrict__ Oh)
{
    const int n  = blockIdx.x * 256 + threadIdx.x;
    const int cg = blockIdx.y;
    const int b  = blockIdx.z;
    const size_t KN = (size_t)CH * NS;
    u16 h[8];
    #pragma unroll
    for (int j = 0; j < 8; ++j) {
        const int c = cg * 8 + j;
        const size_t po = (size_t)b * KN + (size_t)c * NS + n;
        const float mn = MS[po] + MS[po + 4 * KN];
        const float sc = MS[po + 2 * KN] + MS[po + 6 * KN];
        const float ct = content[po];
        const int bc = b * CH + c;
        const float o = sqrtf(fmaxf(sc - mn * mn, 0.f)) * ((ct - cmean[bc]) * cinv[bc]) + mn;
        h[j] = f2h(o);
    }
    const size_t off = (size_t)b * KN + ((size_t)cg * NS + n) * 8;
    *(uint4*)&Oh[off] = *(const uint4*)h;
}

// =====================================================================================
extern "C" void kernel_launch(void* const* d_in, const int* in_sizes, int n_in,
                              void* d_out, int out_size, void* d_ws, size_t ws_size,
                              hipStream_t stream)
{
    const float* content = (const float*)d_in[0];
    const float* style   = (const float*)d_in[1];
    const float* f_w   = (const float*)d_in[2];
    const float* f_b   = (const float*)d_in[3];
    const float* g_w   = (const float*)d_in[4];
    const float* g_b   = (const float*)d_in[5];
    const float* h_w   = (const float*)d_in[6];
    const float* h_b   = (const float*)d_in[7];
    const float* out_w = (const float*)d_in[8];
    const float* out_b = (const float*)d_in[9];
    float* out = (float*)d_out;

    char* ws = (char*)d_ws;
    size_t off = 0;
    auto alloc = [&](size_t bytes) -> void* {
        void* p = ws + off;
        off = (off + bytes + 255) & ~(size_t)255;
        return p;
    };

    const size_t KN   = (size_t)CH * NS;      // 2,097,152 elements (one batch plane)
    const size_t CHCH = (size_t)CH * CH;
    const long   NSNS = (long)NS * NS;

    // ---- weight packs: hi-only, contiguous [Wh0 Wh1 Wh2 Wh3] ----
    u16* Wh0 = (u16*)alloc(4 * CHCH * 2);

    // ---- R2: two time-disjoint layouts:
    //   phase 1 (conv inputs, hi-only):  [Xc_hi | Xs_hi]               (each 2KN)
    //   phase 2 (PV A-packs):            [HvT_hi | Hv2T_hi | Hv2T_lo] (each 2KN)
    u16* R2 = (u16*)alloc(6 * KN * 2);
    u16* Xc_hi = R2;
    u16* Hv2T_hi = R2 + 2 * KN;
    u16* Hv2T_lo = R2 + 4 * KN;

    // ---- R3: [Fqp_hi | Gkp_hi], each 2KN u16; Gkp reused as O pack ----
    u16* Fqp_hi = (u16*)alloc(2 * KN * 2);
    u16* Gkp_hi = (u16*)alloc(2 * KN * 2);
    u16* Op_hi  = Gkp_hi;

    // ---- R5: union: Hv32 fp32 (during convs) -> E16 both batches (67 MB) ----
    char* R5 = (char*)alloc(2 * (size_t)NS * NS * 2);
    float* Hv32 = (float*)(R5 + 4 * KN * 4);   // conv z=4,5 output (dead after pack_hvT)
    u16*   E16  = (u16*)R5;                    // QK output: fp16(exp(s - groupmax)), packed

    // ---- R6: split-K PV partials: [p=0: Mean(2KN) Sec(2KN) | p=1: Mean Sec] ----
    float* MS = (float*)alloc(8 * KN * 4);

    // ---- small ----
    float* pm    = (float*)alloc(2 * 32 * NS * 4);
    float* ps    = (float*)alloc(2 * 32 * NS * 4);
    float* ctab  = (float*)alloc(2 * 32 * NS * 4);
    float* cmean = (float*)alloc(1024 * 4);
    float* cinv  = (float*)alloc(1024 * 4);
    (void)ws_size; (void)in_sizes; (void)n_in; (void)out_size;

    // ================= pipeline =================
    {
        PA4 pa = { { f_w, g_w, h_w, out_w } };
        packA4<<<dim3(8, 8, 4), 256, 0, stream>>>(pa, Wh0);
        PB2 pb = { { content, style } };
        packB4<<<dim3(16, 64, 4), 256, 0, stream>>>(pb, Xc_hi);
    }
    content_stats<<<1024, 256, 0, stream>>>(content, cmean, cinv);

    // ---- merged conv3 (1-term, np=2: Whi*Xhi): z = w*2 + b;
    //      w=0 (f,content)->Fqp hi, w=1 (g,style)->Gkp hi, w=2 (h,style)->Hv32 fp32 ----
    {
        ZTab tb = {};
        const float* bs[3] = { f_b, g_b, h_b };
        for (int z = 0; z < 6; ++z) {
            const int w = z >> 1, b = z & 1;
            tb.aoff[z] = (long)w * CHCH;
            tb.boff[z] = (w == 0 ? 0 : (long)(2 * KN)) + (long)b * KN;
            tb.mode[z] = (w < 2) ? 1 : 0;
            tb.np[z]   = 2;
            tb.ooff[z] = (w < 2) ? ((long)w * 2 * KN + (long)b * KN)   // u16 elems from Fqp_hi
                                 : ((long)4 * KN + (long)b * KN);      // fp32 elems from R5
            tb.bias[z] = bs[w];
        }
        gemm_split<2, false, false, false><<<dim3(32, 4, 6), 256, 0, stream>>>(
            Wh0, nullptr, Xc_hi, nullptr,
            (float*)R5, Fqp_hi, nullptr, nullptr, nullptr, CH, NS, CH, tb);
    }

    // quantized-moments Hv packs (overwrites R2 phase-1; Xc/Xs dead)
    pack_hvT<<<dim3(64, 8, 2), 256, 0, stream>>>(Hv32, R2, Hv2T_hi, Hv2T_lo);

    // ---- merged QK (1-term, np=2, z=2): E16 = fp16(exp(S - 128-group max)), packed;
    //      fused per-128-group col-stats (cross-wave combine in epilogue) ----
    {
        ZTab tq = {};
        for (int z = 0; z < 2; ++z) {
            tq.aoff[z] = (long)z * KN;     // Gk batch
            tq.boff[z] = (long)z * KN;     // Fq batch
            tq.ooff[z] = (long)z * NSNS;   // E16 batch (u16 elems)
            tq.np[z]   = 2;
        }
        gemm_split<2, false, true, false><<<dim3(32, 32, 2), 256, 0, stream>>>(
            Gkp_hi, nullptr, Fqp_hi, nullptr,
            nullptr, E16, pm, ps, nullptr, NS, NS, CH, tq);
    }
    colstats_comb32<<<dim3(16, 2), 256, 0, stream>>>(pm, ps, ctab);

    // ---- fused Mean+Sec PV (split-K x2): z = p*2 + b; K = NS/2 per slice.
    //      Shares the E16 B-tile across Mean (1 term) + Sec (2 terms). ----
    {
        ZTab tp = {};
        for (int z = 0; z < 4; ++z) {
            const int p = z >> 1, b = z & 1;
            tp.aoff[z] = (long)b * KN + (long)p * (KN / 2);
            tp.boff[z] = (long)b * NSNS + (long)p * (NSNS / 2);
            tp.ooff[z] = (long)p * 4 * KN + (long)b * KN;   // Mean; Sec = +2KN in-kernel
            tp.coff[z] = (long)b * 32 * NS + (long)p * 16 * NS;
        }
        gemm_pv<<<dim3(32, 4, 4), 256, 0, stream>>>(
            R2, Hv2T_hi, Hv2T_lo, E16, MS, ctab, NS / 2, tp);
    }

    // O + split-K combine + fused pack (fp16 hi only)
    compute_O_pack<<<dim3(16, 64, 2), 256, 0, stream>>>(
        MS, content, cmean, cinv, Op_hi);

    // ---- out conv (1-term, np=2: Whi*O_hi): bias + residual(content) -> d_out ----
    {
        ZTab tf = {};
        for (int z = 0; z < 2; ++z) {
            tf.aoff[z] = (long)3 * CHCH;
            tf.ooff[z] = (long)z * KN;
            tf.boff[z] = (long)z * KN;
            tf.np[z]   = 2;
            tf.bias[z] = out_b;
        }
        gemm_split<2, true, false, false><<<dim3(32, 4, 2), 256, 0, stream>>>(
            Wh0, nullptr, Op_hi, content,
            out, nullptr, nullptr, nullptr, nullptr, CH, NS, CH, tf);
    }
}